// Round 6
// baseline (1400.623 us; speedup 1.0000x reference)
//
#include <hip/hip_runtime.h>
#include <hip/hip_bf16.h>

// ---------------- constants ----------------
#define C_IN  128
#define C_HID 256
#define C_OUT 128

// ---------------- CSR build ----------------
__global__ void count_kernel(const int* __restrict__ dst, int* __restrict__ cnt, int e, int n) {
    int i = blockIdx.x * blockDim.x + threadIdx.x;
    int stride = gridDim.x * blockDim.x;
    for (; i < e; i += stride) {
        unsigned d = (unsigned)dst[i];
        if (d < (unsigned)n) atomicAdd(&cnt[d], 1);    // clamp: never write OOB
    }
}

__global__ void dinv_kernel(const int* __restrict__ cnt, float* __restrict__ dinv, int n) {
    int i = blockIdx.x * blockDim.x + threadIdx.x;
    if (i < n) dinv[i] = rsqrtf((float)(cnt[i] + 1));   // +1 self loop
}

// single-block exclusive scan of cnt[0..n) -> row_start (and row_pos copy)
__global__ __launch_bounds__(1024) void scan_kernel(const int* __restrict__ cnt,
                                                    int* __restrict__ row_start,
                                                    int* __restrict__ row_pos, int n) {
    __shared__ int wsum[16];
    __shared__ int s_carry;
    const int tid = threadIdx.x, lane = tid & 63, w = tid >> 6;
    if (tid == 0) s_carry = 0;
    __syncthreads();
    for (int base = 0; base < n; base += 1024) {
        int i = base + tid;
        int v = (i < n) ? cnt[i] : 0;
        int x = v;
        #pragma unroll
        for (int off = 1; off < 64; off <<= 1) {
            int y = __shfl_up(x, off);
            if (lane >= off) x += y;
        }
        if (lane == 63) wsum[w] = x;
        __syncthreads();                       // wsum visible
        int woff = 0, total = 0;
        #pragma unroll
        for (int j = 0; j < 16; ++j) {
            int s = wsum[j];
            if (j < w) woff += s;
            total += s;
        }
        int excl = s_carry + woff + (x - v);
        if (i < n) { row_start[i] = excl; row_pos[i] = excl; }
        __syncthreads();                       // all reads of wsum/s_carry done
        if (tid == 0) s_carry += total;
        __syncthreads();                       // s_carry updated before reuse
    }
    if (tid == 0) row_start[n] = s_carry;
}

__global__ void fill_kernel(const int* __restrict__ src, const int* __restrict__ dst,
                            int* __restrict__ row_pos, int* __restrict__ csr_src, int e, int n) {
    int i = blockIdx.x * blockDim.x + threadIdx.x;
    int stride = gridDim.x * blockDim.x;
    for (; i < e; i += stride) {
        unsigned d = (unsigned)dst[i];
        unsigned s = (unsigned)src[i];
        if (d < (unsigned)n && s < (unsigned)n) {      // clamp: never write OOB
            int p = atomicAdd(&row_pos[d], 1);
            csr_src[p] = (int)s;
        }
    }
}

// ---------------- GEMM: C[n,M] = A[n,K] @ W[K,M] ----------------
// Block: 256 threads (4 waves). Each wave computes ROWS_PER_WAVE rows x 128 cols
// (2 cols/lane). W staged in LDS in K-chunks of 128 (64 KB).
template<int K, int ROWS_PER_WAVE>
__global__ __launch_bounds__(256) void gemm_kernel(const float* __restrict__ A,
                                                   const float* __restrict__ W,
                                                   float* __restrict__ C, int n, int M) {
    constexpr int KC = 128;
    constexpr int MC = 128;
    __shared__ float wl[KC * MC];               // 64 KB
    const int col0 = blockIdx.y * MC;
    const int lane = threadIdx.x & 63;
    const int wid  = threadIdx.x >> 6;
    const int rows_per_block = 4 * ROWS_PER_WAVE;

    for (int rg = blockIdx.x; rg * rows_per_block < n; rg += gridDim.x) {
        int row0 = rg * rows_per_block + wid * ROWS_PER_WAVE;
        row0 = __builtin_amdgcn_readfirstlane(row0);   // scalarize A loads
        float2 acc[ROWS_PER_WAVE];
        #pragma unroll
        for (int r = 0; r < ROWS_PER_WAVE; ++r) { acc[r].x = 0.f; acc[r].y = 0.f; }

        for (int kc = 0; kc < K; kc += KC) {
            __syncthreads();
            // stage W[kc:kc+KC, col0:col0+MC] : 16384 floats, 16 float4/thread
            #pragma unroll
            for (int i = threadIdx.x; i < KC * MC / 4; i += 256) {
                int k = (i * 4) / MC;
                int c = (i * 4) % MC;
                *(float4*)&wl[i * 4] = *(const float4*)&W[(size_t)(kc + k) * M + col0 + c];
            }
            __syncthreads();
            #pragma unroll 4
            for (int k = 0; k < KC; ++k) {
                float2 wv = *(const float2*)&wl[k * MC + lane * 2];
                #pragma unroll
                for (int r = 0; r < ROWS_PER_WAVE; ++r) {
                    int row = row0 + r;
                    float a = (row < n) ? A[(size_t)row * K + kc + k] : 0.f;
                    acc[r].x += a * wv.x;
                    acc[r].y += a * wv.y;
                }
            }
        }
        #pragma unroll
        for (int r = 0; r < ROWS_PER_WAVE; ++r) {
            int row = row0 + r;
            if (row < n)
                *(float2*)&C[(size_t)row * M + col0 + lane * 2] = acc[r];
        }
    }
}

// ---------------- aggregation: out[n] = bias + dinv[n]^2*H[n] + sum_e dinv[s]*dinv[n]*H[s]
template<int CH, int VEC, bool RELU>
__global__ __launch_bounds__(256) void agg_kernel(const float* __restrict__ H,
                                                  const int* __restrict__ row_start,
                                                  const int* __restrict__ csr_src,
                                                  const float* __restrict__ dinv,
                                                  const float* __restrict__ bias,
                                                  float* __restrict__ out, int n) {
    int node = blockIdx.x * 4 + (threadIdx.x >> 6);
    node = __builtin_amdgcn_readfirstlane(node);
    if (node >= n) return;
    const int lane = threadIdx.x & 63;
    const int c0 = lane * VEC;

    const float dn = dinv[node];
    const int e0 = row_start[node], e1 = row_start[node + 1];

    float acc[VEC];
    {   // self loop
        float c = dn * dn;
        #pragma unroll
        for (int v = 0; v < VEC; ++v) acc[v] = H[(size_t)node * CH + c0 + v] * c;
    }
    for (int e = e0; e < e1; ++e) {
        unsigned s = (unsigned)csr_src[e];
        if (s >= (unsigned)n) continue;                 // clamp: never read OOB
        float c = dinv[s] * dn;
        const float* hp = &H[(size_t)s * CH + c0];
        if (VEC == 4) {
            float4 h4 = *(const float4*)hp;
            acc[0] += h4.x * c; acc[1] += h4.y * c;
            acc[2] += h4.z * c; acc[3] += h4.w * c;
        } else {
            float2 h2 = *(const float2*)hp;
            acc[0] += h2.x * c; acc[1] += h2.y * c;
        }
    }
    #pragma unroll
    for (int v = 0; v < VEC; ++v) {
        float o = acc[v] + bias[c0 + v];
        if (RELU) o = fmaxf(o, 0.f);
        out[(size_t)node * CH + c0 + v] = o;
    }
}

// ---------------- layernorm in-place on [n,128] ----------------
__global__ __launch_bounds__(256) void ln_kernel(float* __restrict__ out,
                                                 const float* __restrict__ gamma,
                                                 const float* __restrict__ beta, int n) {
    int row = blockIdx.x * 4 + (threadIdx.x >> 6);
    if (row >= n) return;
    const int lane = threadIdx.x & 63;
    float2 v = *(float2*)&out[(size_t)row * 128 + lane * 2];
    float s  = v.x + v.y;
    float ss = v.x * v.x + v.y * v.y;
    #pragma unroll
    for (int off = 32; off; off >>= 1) {
        s  += __shfl_xor(s, off);
        ss += __shfl_xor(ss, off);
    }
    float mu  = s * (1.f / 128.f);
    float var = ss * (1.f / 128.f) - mu * mu;
    float rstd = rsqrtf(var + 1e-5f);
    float2 g = *(const float2*)&gamma[lane * 2];
    float2 b = *(const float2*)&beta[lane * 2];
    float2 o;
    o.x = (v.x - mu) * rstd * g.x + b.x;
    o.y = (v.y - mu) * rstd * g.y + b.y;
    *(float2*)&out[(size_t)row * 128 + lane * 2] = o;
}

extern "C" void kernel_launch(void* const* d_in, const int* in_sizes, int n_in,
                              void* d_out, int out_size, void* d_ws, size_t ws_size,
                              hipStream_t stream) {
    const float* x     = (const float*)d_in[0];
    const int*   ei    = (const int*)d_in[1];     // int32 (harness: integer -> const int*)
    const float* W1    = (const float*)d_in[2];
    const float* b1    = (const float*)d_in[3];
    const float* W2    = (const float*)d_in[4];
    const float* b2    = (const float*)d_in[5];
    const float* gamma = (const float*)d_in[6];
    const float* beta  = (const float*)d_in[7];
    float* out = (float*)d_out;

    const int N = in_sizes[0] / C_IN;
    const int E = in_sizes[1] / 2;
    const int* src = ei;
    const int* dst = ei + E;

    // workspace layout
    float* h_buf = (float*)d_ws;                 // N*256
    float* g_buf = h_buf + (size_t)N * C_HID;    // N*256
    float* dinv  = g_buf + (size_t)N * C_HID;    // N
    int*   cnt   = (int*)(dinv + N);             // N
    int*   row_start = cnt + N;                  // N+1 (pad 4)
    int*   row_pos   = row_start + N + 4;        // N
    int*   csr_src   = row_pos + N;              // E

    hipMemsetAsync(cnt, 0, (size_t)N * sizeof(int), stream);

    count_kernel<<<2048, 256, 0, stream>>>(dst, cnt, E, N);
    dinv_kernel<<<(N + 255) / 256, 256, 0, stream>>>(cnt, dinv, N);
    scan_kernel<<<1, 1024, 0, stream>>>(cnt, row_start, row_pos, N);
    fill_kernel<<<2048, 256, 0, stream>>>(src, dst, row_pos, csr_src, E, N);

    // layer 1: h1 = x @ W1 ; g1 = relu(agg(h1) + b1)
    {
        dim3 grid((N + 31) / 32, C_HID / 128);
        gemm_kernel<C_IN, 8><<<grid, 256, 0, stream>>>(x, W1, h_buf, N, C_HID);
    }
    agg_kernel<C_HID, 4, true><<<(N + 3) / 4, 256, 0, stream>>>(
        h_buf, row_start, csr_src, dinv, b1, g_buf, N);

    // layer 2: h2 = g1 @ W2 ; out = agg(h2) + b2 ; LN in place
    {
        dim3 grid((N + 31) / 32, C_OUT / 128);
        gemm_kernel<C_HID, 8><<<grid, 256, 0, stream>>>(g_buf, W2, h_buf, N, C_OUT);
    }
    agg_kernel<C_OUT, 2, false><<<(N + 3) / 4, 256, 0, stream>>>(
        h_buf, row_start, csr_src, dinv, b2, out, N);

    ln_kernel<<<(N + 3) / 4, 256, 0, stream>>>(out, gamma, beta, N);
}

// Round 7
// 783.970 us; speedup vs baseline: 1.7866x; 1.7866x over previous
//
#include <hip/hip_runtime.h>
#include <hip/hip_bf16.h>

// ---------------- constants ----------------
#define C_IN  128
#define C_HID 256
#define C_OUT 128

typedef __attribute__((ext_vector_type(8))) short short8;
typedef __attribute__((ext_vector_type(4))) float f32x4;

static __device__ __forceinline__ unsigned short f2bf(float f) {
    __hip_bfloat16 h = __float2bfloat16(f);
    return __builtin_bit_cast(unsigned short, h);
}

// ---------------- CSR build ----------------
__global__ void count_kernel(const int* __restrict__ dst, int* __restrict__ cnt, int e, int n) {
    int i = blockIdx.x * blockDim.x + threadIdx.x;
    int stride = gridDim.x * blockDim.x;
    for (; i < e; i += stride) {
        unsigned d = (unsigned)dst[i];
        if (d < (unsigned)n) atomicAdd(&cnt[d], 1);
    }
}

__global__ void dinv_kernel(const int* __restrict__ cnt, float* __restrict__ dinv, int n) {
    int i = blockIdx.x * blockDim.x + threadIdx.x;
    if (i < n) dinv[i] = rsqrtf((float)(cnt[i] + 1));   // +1 self loop
}

__global__ __launch_bounds__(1024) void scan_kernel(const int* __restrict__ cnt,
                                                    int* __restrict__ row_start,
                                                    int* __restrict__ row_pos, int n) {
    __shared__ int wsum[16];
    __shared__ int s_carry;
    const int tid = threadIdx.x, lane = tid & 63, w = tid >> 6;
    if (tid == 0) s_carry = 0;
    __syncthreads();
    for (int base = 0; base < n; base += 1024) {
        int i = base + tid;
        int v = (i < n) ? cnt[i] : 0;
        int x = v;
        #pragma unroll
        for (int off = 1; off < 64; off <<= 1) {
            int y = __shfl_up(x, off);
            if (lane >= off) x += y;
        }
        if (lane == 63) wsum[w] = x;
        __syncthreads();
        int woff = 0, total = 0;
        #pragma unroll
        for (int j = 0; j < 16; ++j) {
            int s = wsum[j];
            if (j < w) woff += s;
            total += s;
        }
        int excl = s_carry + woff + (x - v);
        if (i < n) { row_start[i] = excl; row_pos[i] = excl; }
        __syncthreads();
        if (tid == 0) s_carry += total;
        __syncthreads();
    }
    if (tid == 0) row_start[n] = s_carry;
}

__global__ void fill_kernel(const int* __restrict__ src, const int* __restrict__ dst,
                            int* __restrict__ row_pos, int* __restrict__ csr_src, int e, int n) {
    int i = blockIdx.x * blockDim.x + threadIdx.x;
    int stride = gridDim.x * blockDim.x;
    for (; i < e; i += stride) {
        unsigned d = (unsigned)dst[i];
        unsigned s = (unsigned)src[i];
        if (d < (unsigned)n && s < (unsigned)n) {
            int p = atomicAdd(&row_pos[d], 1);
            csr_src[p] = (int)s;
        }
    }
}

// ---------------- f32 -> bf16 convert (vectorized) ----------------
__global__ void cvt_bf16_kernel(const float* __restrict__ in, unsigned short* __restrict__ out,
                                int n4) {   // n4 = total/4
    int i = blockIdx.x * blockDim.x + threadIdx.x;
    int stride = gridDim.x * blockDim.x;
    for (; i < n4; i += stride) {
        float4 v = *(const float4*)&in[(size_t)i * 4];
        ushort4 o;
        o.x = f2bf(v.x); o.y = f2bf(v.y); o.z = f2bf(v.z); o.w = f2bf(v.w);
        *(ushort4*)&out[(size_t)i * 4] = o;
    }
}

// ---------------- pack W [K][M] f32 -> MFMA-fragment-ordered bf16 ----------------
// flat o = ((ct*NKS + ks)*64 + lane)*8 + j  maps to  W[ks*32 + (lane>>4)*8 + j][ct*16 + (lane&15)]
template<int K, int M>
__global__ void pack_w_kernel(const float* __restrict__ W, unsigned short* __restrict__ Wp) {
    int o = blockIdx.x * 256 + threadIdx.x;
    if (o >= K * M) return;
    constexpr int NKS = K / 32;
    int j    = o & 7;
    int lane = (o >> 3) & 63;
    int rest = o >> 9;
    int ks = rest % NKS;
    int ct = rest / NKS;
    int k = ks * 32 + (lane >> 4) * 8 + j;
    int m = ct * 16 + (lane & 15);
    Wp[o] = f2bf(W[(size_t)k * M + m]);
}

// ---------------- MFMA GEMM: C[n,M] f32 = A[n,K] bf16 @ W[K,M] (packed bf16) ----------------
// 256 threads / 4 waves. W fully staged in LDS (64 KB) once per block.
// Wave w handles rows [tile*64 + w*16, +16) x all M cols (M/16 col-tiles).
template<int K, int M>
__global__ __launch_bounds__(256) void gemm_mfma_kernel(const unsigned short* __restrict__ A,
                                                        const unsigned short* __restrict__ Wp,
                                                        float* __restrict__ C, int n) {
    constexpr int NKS = K / 32;
    constexpr int NCT = M / 16;
    __shared__ unsigned short wl[K * M];            // 64 KB
    const int tid  = threadIdx.x;
    const int lane = tid & 63;
    const int wid  = tid >> 6;

    // stage packed W linearly: 16 B per thread per iter
    for (int i = tid; i < K * M / 8; i += 256)
        *(uint4*)&wl[(size_t)i * 8] = *(const uint4*)&Wp[(size_t)i * 8];
    __syncthreads();

    const int ntiles = (n + 63) / 64;
    for (int t = blockIdx.x; t < ntiles; t += gridDim.x) {
        const int row0 = t * 64 + wid * 16;
        int arow = row0 + (lane & 15);
        if (arow > n - 1) arow = n - 1;             // clamp (garbage rows masked at store)
        const unsigned short* ap = A + (size_t)arow * K + (lane >> 4) * 8;

        short8 afrag[NKS];
        #pragma unroll
        for (int ks = 0; ks < NKS; ++ks)
            afrag[ks] = *(const short8*)(ap + ks * 32);

        f32x4 acc[NCT] = {};
        #pragma unroll
        for (int ks = 0; ks < NKS; ++ks) {
            #pragma unroll
            for (int ct = 0; ct < NCT; ++ct) {
                short8 b = *(const short8*)&wl[((ct * NKS + ks) * 64 + lane) * 8];
                acc[ct] = __builtin_amdgcn_mfma_f32_16x16x32_bf16(afrag[ks], b, acc[ct], 0, 0, 0);
            }
        }

        // C/D layout: col = lane&15, row = (lane>>4)*4 + r   [verified m89]
        const int crow0 = row0 + (lane >> 4) * 4;
        const int ccol  = lane & 15;
        #pragma unroll
        for (int ct = 0; ct < NCT; ++ct) {
            #pragma unroll
            for (int r = 0; r < 4; ++r) {
                int row = crow0 + r;
                if (row < n)
                    C[(size_t)row * M + ct * 16 + ccol] = acc[ct][r];
            }
        }
    }
}

// ---------------- aggregation: out[n] = bias + dinv[n]^2*H[n] + sum_e dinv[s]*dinv[n]*H[s]
template<int CH, int VEC, bool RELU, bool OUT_BF16>
__global__ __launch_bounds__(256) void agg_kernel(const float* __restrict__ H,
                                                  const int* __restrict__ row_start,
                                                  const int* __restrict__ csr_src,
                                                  const float* __restrict__ dinv,
                                                  const float* __restrict__ bias,
                                                  void* __restrict__ out_v, int n) {
    int node = blockIdx.x * 4 + (threadIdx.x >> 6);
    node = __builtin_amdgcn_readfirstlane(node);
    if (node >= n) return;
    const int lane = threadIdx.x & 63;
    const int c0 = lane * VEC;

    const float dn = dinv[node];
    const int e0 = row_start[node], e1 = row_start[node + 1];

    float acc[VEC];
    {   // self loop
        float c = dn * dn;
        #pragma unroll
        for (int v = 0; v < VEC; ++v) acc[v] = H[(size_t)node * CH + c0 + v] * c;
    }
    for (int e = e0; e < e1; ++e) {
        unsigned s = (unsigned)csr_src[e];
        if (s >= (unsigned)n) continue;
        float c = dinv[s] * dn;
        const float* hp = &H[(size_t)s * CH + c0];
        if (VEC == 4) {
            float4 h4 = *(const float4*)hp;
            acc[0] += h4.x * c; acc[1] += h4.y * c;
            acc[2] += h4.z * c; acc[3] += h4.w * c;
        } else {
            float2 h2 = *(const float2*)hp;
            acc[0] += h2.x * c; acc[1] += h2.y * c;
        }
    }
    #pragma unroll
    for (int v = 0; v < VEC; ++v) {
        acc[v] += bias[c0 + v];
        if (RELU) acc[v] = fmaxf(acc[v], 0.f);
    }
    if (OUT_BF16) {
        unsigned short* out = (unsigned short*)out_v;
        if (VEC == 4) {
            ushort4 o4;
            o4.x = f2bf(acc[0]); o4.y = f2bf(acc[1]);
            o4.z = f2bf(acc[2]); o4.w = f2bf(acc[3]);
            *(ushort4*)&out[(size_t)node * CH + c0] = o4;
        } else {
            #pragma unroll
            for (int v = 0; v < VEC; ++v) out[(size_t)node * CH + c0 + v] = f2bf(acc[v]);
        }
    } else {
        float* out = (float*)out_v;
        #pragma unroll
        for (int v = 0; v < VEC; ++v) out[(size_t)node * CH + c0 + v] = acc[v];
    }
}

// ---------------- layernorm in-place on [n,128] ----------------
__global__ __launch_bounds__(256) void ln_kernel(float* __restrict__ out,
                                                 const float* __restrict__ gamma,
                                                 const float* __restrict__ beta, int n) {
    int row = blockIdx.x * 4 + (threadIdx.x >> 6);
    if (row >= n) return;
    const int lane = threadIdx.x & 63;
    float2 v = *(float2*)&out[(size_t)row * 128 + lane * 2];
    float s  = v.x + v.y;
    float ss = v.x * v.x + v.y * v.y;
    #pragma unroll
    for (int off = 32; off; off >>= 1) {
        s  += __shfl_xor(s, off);
        ss += __shfl_xor(ss, off);
    }
    float mu  = s * (1.f / 128.f);
    float var = ss * (1.f / 128.f) - mu * mu;
    float rstd = rsqrtf(var + 1e-5f);
    float2 g = *(const float2*)&gamma[lane * 2];
    float2 b = *(const float2*)&beta[lane * 2];
    float2 o;
    o.x = (v.x - mu) * rstd * g.x + b.x;
    o.y = (v.y - mu) * rstd * g.y + b.y;
    *(float2*)&out[(size_t)row * 128 + lane * 2] = o;
}

extern "C" void kernel_launch(void* const* d_in, const int* in_sizes, int n_in,
                              void* d_out, int out_size, void* d_ws, size_t ws_size,
                              hipStream_t stream) {
    const float* x     = (const float*)d_in[0];
    const int*   ei    = (const int*)d_in[1];     // int32 (harness: integer -> const int*)
    const float* W1    = (const float*)d_in[2];
    const float* b1    = (const float*)d_in[3];
    const float* W2    = (const float*)d_in[4];
    const float* b2    = (const float*)d_in[5];
    const float* gamma = (const float*)d_in[6];
    const float* beta  = (const float*)d_in[7];
    float* out = (float*)d_out;

    const int N = in_sizes[0] / C_IN;
    const int E = in_sizes[1] / 2;
    const int* src = ei;
    const int* dst = ei + E;

    // workspace layout
    float*          h_buf = (float*)d_ws;                       // N*256 f32 (gemm1 out; gemm2 out reuses)
    unsigned short* g16   = (unsigned short*)(h_buf + (size_t)N * C_HID);  // N*256 bf16
    unsigned short* x16   = g16 + (size_t)N * C_HID;            // N*128 bf16
    unsigned short* w1p   = x16 + (size_t)N * C_IN;             // 128*256
    unsigned short* w2p   = w1p + C_IN * C_HID;                 // 256*128
    float* dinv  = (float*)(w2p + C_HID * C_OUT);               // N
    int*   cnt   = (int*)(dinv + N);                            // N
    int*   row_start = cnt + N;                                 // N+1 (pad 4)
    int*   row_pos   = row_start + N + 4;                       // N
    int*   csr_src   = row_pos + N;                             // E

    hipMemsetAsync(cnt, 0, (size_t)N * sizeof(int), stream);

    count_kernel<<<2048, 256, 0, stream>>>(dst, cnt, E, N);
    dinv_kernel<<<(N + 255) / 256, 256, 0, stream>>>(cnt, dinv, N);
    scan_kernel<<<1, 1024, 0, stream>>>(cnt, row_start, row_pos, N);
    fill_kernel<<<2048, 256, 0, stream>>>(src, dst, row_pos, csr_src, E, N);

    // input conversions / weight packing
    cvt_bf16_kernel<<<2048, 256, 0, stream>>>(x, x16, N * C_IN / 4);
    pack_w_kernel<C_IN, C_HID><<<(C_IN * C_HID + 255) / 256, 256, 0, stream>>>(W1, w1p);
    pack_w_kernel<C_HID, C_OUT><<<(C_HID * C_OUT + 255) / 256, 256, 0, stream>>>(W2, w2p);

    // layer 1: h1 = x @ W1 (MFMA) ; g = relu(agg(h1) + b1) -> bf16
    gemm_mfma_kernel<C_IN, C_HID><<<512, 256, 0, stream>>>(x16, w1p, h_buf, N);
    agg_kernel<C_HID, 4, true, true><<<(N + 3) / 4, 256, 0, stream>>>(
        h_buf, row_start, csr_src, dinv, b1, (void*)g16, N);

    // layer 2: h2 = g @ W2 (MFMA) ; out = agg(h2) + b2 ; LN in place
    gemm_mfma_kernel<C_HID, C_OUT><<<512, 256, 0, stream>>>(g16, w2p, h_buf, N);
    agg_kernel<C_OUT, 2, false, false><<<(N + 3) / 4, 256, 0, stream>>>(
        h_buf, row_start, csr_src, dinv, b2, (void*)out, N);

    ln_kernel<<<(N + 3) / 4, 256, 0, stream>>>(out, gamma, beta, N);
}

// Round 8
// 619.393 us; speedup vs baseline: 2.2613x; 1.2657x over previous
//
#include <hip/hip_runtime.h>
#include <hip/hip_bf16.h>

// ---------------- constants ----------------
#define C_IN  128
#define C_HID 256
#define C_OUT 128

typedef __attribute__((ext_vector_type(8))) short short8;
typedef __attribute__((ext_vector_type(4))) float f32x4;

static __device__ __forceinline__ unsigned short f2bf(float f) {
    __hip_bfloat16 h = __float2bfloat16(f);
    return __builtin_bit_cast(unsigned short, h);
}
static __device__ __forceinline__ float bf2f(unsigned short u) {
    unsigned int x = ((unsigned int)u) << 16;
    return __builtin_bit_cast(float, x);
}

// ---------------- CSR build ----------------
__global__ void count_kernel(const int* __restrict__ dst, int* __restrict__ cnt, int e, int n) {
    int i = blockIdx.x * blockDim.x + threadIdx.x;
    int stride = gridDim.x * blockDim.x;
    for (; i < e; i += stride) {
        unsigned d = (unsigned)dst[i];
        if (d < (unsigned)n) atomicAdd(&cnt[d], 1);
    }
}

__global__ void dinv_kernel(const int* __restrict__ cnt, float* __restrict__ dinv, int n) {
    int i = blockIdx.x * blockDim.x + threadIdx.x;
    if (i < n) dinv[i] = rsqrtf((float)(cnt[i] + 1));   // +1 self loop
}

__global__ __launch_bounds__(1024) void scan_kernel(const int* __restrict__ cnt,
                                                    int* __restrict__ row_start,
                                                    int* __restrict__ row_pos, int n) {
    __shared__ int wsum[16];
    __shared__ int s_carry;
    const int tid = threadIdx.x, lane = tid & 63, w = tid >> 6;
    if (tid == 0) s_carry = 0;
    __syncthreads();
    for (int base = 0; base < n; base += 1024) {
        int i = base + tid;
        int v = (i < n) ? cnt[i] : 0;
        int x = v;
        #pragma unroll
        for (int off = 1; off < 64; off <<= 1) {
            int y = __shfl_up(x, off);
            if (lane >= off) x += y;
        }
        if (lane == 63) wsum[w] = x;
        __syncthreads();
        int woff = 0, total = 0;
        #pragma unroll
        for (int j = 0; j < 16; ++j) {
            int s = wsum[j];
            if (j < w) woff += s;
            total += s;
        }
        int excl = s_carry + woff + (x - v);
        if (i < n) { row_start[i] = excl; row_pos[i] = excl; }
        __syncthreads();
        if (tid == 0) s_carry += total;
        __syncthreads();
    }
    if (tid == 0) row_start[n] = s_carry;
}

__global__ void fill_kernel(const int* __restrict__ src, const int* __restrict__ dst,
                            int* __restrict__ row_pos, int* __restrict__ csr_src, int e, int n) {
    int i = blockIdx.x * blockDim.x + threadIdx.x;
    int stride = gridDim.x * blockDim.x;
    for (; i < e; i += stride) {
        unsigned d = (unsigned)dst[i];
        unsigned s = (unsigned)src[i];
        if (d < (unsigned)n && s < (unsigned)n) {
            int p = atomicAdd(&row_pos[d], 1);
            csr_src[p] = (int)s;
        }
    }
}

// ---------------- f32 -> bf16 convert (vectorized) ----------------
__global__ void cvt_bf16_kernel(const float* __restrict__ in, unsigned short* __restrict__ out,
                                int n4) {   // n4 = total/4
    int i = blockIdx.x * blockDim.x + threadIdx.x;
    int stride = gridDim.x * blockDim.x;
    for (; i < n4; i += stride) {
        float4 v = *(const float4*)&in[(size_t)i * 4];
        ushort4 o;
        o.x = f2bf(v.x); o.y = f2bf(v.y); o.z = f2bf(v.z); o.w = f2bf(v.w);
        *(ushort4*)&out[(size_t)i * 4] = o;
    }
}

// ---------------- pack W [K][M] f32 -> MFMA-fragment-ordered bf16 ----------------
// flat o = ((ct*NKS + ks)*64 + lane)*8 + j  maps to  W[ks*32 + (lane>>4)*8 + j][ct*16 + (lane&15)]
template<int K, int M>
__global__ void pack_w_kernel(const float* __restrict__ W, unsigned short* __restrict__ Wp) {
    int o = blockIdx.x * 256 + threadIdx.x;
    if (o >= K * M) return;
    constexpr int NKS = K / 32;
    int j    = o & 7;
    int lane = (o >> 3) & 63;
    int rest = o >> 9;
    int ks = rest % NKS;
    int ct = rest / NKS;
    int k = ks * 32 + (lane >> 4) * 8 + j;
    int m = ct * 16 + (lane & 15);
    Wp[o] = f2bf(W[(size_t)k * M + m]);
}

// ---------------- MFMA GEMM: C[n,M] bf16 = A[n,K] bf16 @ W[K,M] (packed bf16) ----------------
// 256 threads / 4 waves. W fully staged in LDS (64 KB) once per block.
// Wave w handles rows [tile*64 + w*16, +16) x all M cols (M/16 col-tiles).
template<int K, int M>
__global__ __launch_bounds__(256) void gemm_mfma_kernel(const unsigned short* __restrict__ A,
                                                        const unsigned short* __restrict__ Wp,
                                                        unsigned short* __restrict__ C, int n) {
    constexpr int NKS = K / 32;
    constexpr int NCT = M / 16;
    __shared__ unsigned short wl[K * M];            // 64 KB
    const int tid  = threadIdx.x;
    const int lane = tid & 63;
    const int wid  = tid >> 6;

    // stage packed W linearly: 16 B per thread per iter
    for (int i = tid; i < K * M / 8; i += 256)
        *(uint4*)&wl[(size_t)i * 8] = *(const uint4*)&Wp[(size_t)i * 8];
    __syncthreads();

    const int ntiles = (n + 63) / 64;
    for (int t = blockIdx.x; t < ntiles; t += gridDim.x) {
        const int row0 = t * 64 + wid * 16;
        int arow = row0 + (lane & 15);
        if (arow > n - 1) arow = n - 1;             // clamp (garbage rows masked at store)
        const unsigned short* ap = A + (size_t)arow * K + (lane >> 4) * 8;

        short8 afrag[NKS];
        #pragma unroll
        for (int ks = 0; ks < NKS; ++ks)
            afrag[ks] = *(const short8*)(ap + ks * 32);

        f32x4 acc[NCT] = {};
        #pragma unroll
        for (int ks = 0; ks < NKS; ++ks) {
            #pragma unroll
            for (int ct = 0; ct < NCT; ++ct) {
                short8 b = *(const short8*)&wl[((ct * NKS + ks) * 64 + lane) * 8];
                acc[ct] = __builtin_amdgcn_mfma_f32_16x16x32_bf16(afrag[ks], b, acc[ct], 0, 0, 0);
            }
        }

        // C/D layout: col = lane&15, row = (lane>>4)*4 + r   [verified m89]
        const int crow0 = row0 + (lane >> 4) * 4;
        const int ccol  = lane & 15;
        #pragma unroll
        for (int ct = 0; ct < NCT; ++ct) {
            #pragma unroll
            for (int r = 0; r < 4; ++r) {
                int row = crow0 + r;
                if (row < n)
                    C[(size_t)row * M + ct * 16 + ccol] = f2bf(acc[ct][r]);
            }
        }
    }
}

// ---------------- aggregation (bf16 H): out = bias + dinv[n]^2*H[n] + sum dinv[s]*dinv[n]*H[s]
// VEC channels per lane. Optional ReLU. Optional fused LayerNorm epilogue (CH==128 only:
// one wave holds the full row). Output: bf16 (no LN) or f32 (LN).
template<int CH, int VEC, bool RELU, bool LN>
__global__ __launch_bounds__(256) void agg_kernel(const unsigned short* __restrict__ H,
                                                  const int* __restrict__ row_start,
                                                  const int* __restrict__ csr_src,
                                                  const float* __restrict__ dinv,
                                                  const float* __restrict__ bias,
                                                  const float* __restrict__ gamma,
                                                  const float* __restrict__ beta,
                                                  void* __restrict__ out_v, int n) {
    int node = blockIdx.x * 4 + (threadIdx.x >> 6);
    node = __builtin_amdgcn_readfirstlane(node);
    if (node >= n) return;
    const int lane = threadIdx.x & 63;
    const int c0 = lane * VEC;

    const float dn = dinv[node];
    const int e0 = row_start[node], e1 = row_start[node + 1];

    float acc[VEC];
    {   // self loop
        float c = dn * dn;
        if (VEC == 4) {
            ushort4 h = *(const ushort4*)&H[(size_t)node * CH + c0];
            acc[0] = bf2f(h.x) * c; acc[1] = bf2f(h.y) * c;
            acc[2] = bf2f(h.z) * c; acc[3] = bf2f(h.w) * c;
        } else {
            ushort2 h = *(const ushort2*)&H[(size_t)node * CH + c0];
            acc[0] = bf2f(h.x) * c; acc[1] = bf2f(h.y) * c;
        }
    }
    for (int e = e0; e < e1; ++e) {
        unsigned s = (unsigned)csr_src[e];
        if (s >= (unsigned)n) continue;
        float c = dinv[s] * dn;
        const unsigned short* hp = &H[(size_t)s * CH + c0];
        if (VEC == 4) {
            ushort4 h = *(const ushort4*)hp;
            acc[0] += bf2f(h.x) * c; acc[1] += bf2f(h.y) * c;
            acc[2] += bf2f(h.z) * c; acc[3] += bf2f(h.w) * c;
        } else {
            ushort2 h = *(const ushort2*)hp;
            acc[0] += bf2f(h.x) * c; acc[1] += bf2f(h.y) * c;
        }
    }
    #pragma unroll
    for (int v = 0; v < VEC; ++v) {
        acc[v] += bias[c0 + v];
        if (RELU) acc[v] = fmaxf(acc[v], 0.f);
    }

    if (LN) {
        // fused LayerNorm: wave holds the full CH=128 row (VEC=2)
        float s = 0.f, ss = 0.f;
        #pragma unroll
        for (int v = 0; v < VEC; ++v) { s += acc[v]; ss += acc[v] * acc[v]; }
        #pragma unroll
        for (int off = 32; off; off >>= 1) {
            s  += __shfl_xor(s, off);
            ss += __shfl_xor(ss, off);
        }
        float mu  = s * (1.f / (float)CH);
        float var = ss * (1.f / (float)CH) - mu * mu;
        float rstd = rsqrtf(var + 1e-5f);
        float* out = (float*)out_v;
        float2 g = *(const float2*)&gamma[c0];
        float2 b = *(const float2*)&beta[c0];
        float2 o;
        o.x = (acc[0] - mu) * rstd * g.x + b.x;
        o.y = (acc[1] - mu) * rstd * g.y + b.y;
        *(float2*)&out[(size_t)node * CH + c0] = o;
    } else {
        unsigned short* out = (unsigned short*)out_v;
        if (VEC == 4) {
            ushort4 o4;
            o4.x = f2bf(acc[0]); o4.y = f2bf(acc[1]);
            o4.z = f2bf(acc[2]); o4.w = f2bf(acc[3]);
            *(ushort4*)&out[(size_t)node * CH + c0] = o4;
        } else {
            #pragma unroll
            for (int v = 0; v < VEC; ++v) out[(size_t)node * CH + c0 + v] = f2bf(acc[v]);
        }
    }
}

extern "C" void kernel_launch(void* const* d_in, const int* in_sizes, int n_in,
                              void* d_out, int out_size, void* d_ws, size_t ws_size,
                              hipStream_t stream) {
    const float* x     = (const float*)d_in[0];
    const int*   ei    = (const int*)d_in[1];     // int32 (harness: integer -> const int*)
    const float* W1    = (const float*)d_in[2];
    const float* b1    = (const float*)d_in[3];
    const float* W2    = (const float*)d_in[4];
    const float* b2    = (const float*)d_in[5];
    const float* gamma = (const float*)d_in[6];
    const float* beta  = (const float*)d_in[7];
    float* out = (float*)d_out;

    const int N = in_sizes[0] / C_IN;
    const int E = in_sizes[1] / 2;
    const int* src = ei;
    const int* dst = ei + E;

    // workspace layout (all bf16 intermediates)
    unsigned short* h16 = (unsigned short*)d_ws;            // N*256 (gemm1 out / gemm2 out reuse)
    unsigned short* g16 = h16 + (size_t)N * C_HID;          // N*256 (agg1 out, gemm2 in)
    unsigned short* x16 = g16 + (size_t)N * C_HID;          // N*128
    unsigned short* w1p = x16 + (size_t)N * C_IN;           // 128*256
    unsigned short* w2p = w1p + C_IN * C_HID;               // 256*128
    float* dinv  = (float*)(w2p + C_HID * C_OUT);           // N
    int*   cnt   = (int*)(dinv + N);                        // N
    int*   row_start = cnt + N;                             // N+1 (pad 4)
    int*   row_pos   = row_start + N + 4;                   // N
    int*   csr_src   = row_pos + N;                         // E

    hipMemsetAsync(cnt, 0, (size_t)N * sizeof(int), stream);

    count_kernel<<<2048, 256, 0, stream>>>(dst, cnt, E, N);
    dinv_kernel<<<(N + 255) / 256, 256, 0, stream>>>(cnt, dinv, N);
    scan_kernel<<<1, 1024, 0, stream>>>(cnt, row_start, row_pos, N);
    fill_kernel<<<2048, 256, 0, stream>>>(src, dst, row_pos, csr_src, E, N);

    // input conversions / weight packing
    cvt_bf16_kernel<<<2048, 256, 0, stream>>>(x, x16, N * C_IN / 4);
    pack_w_kernel<C_IN, C_HID><<<(C_IN * C_HID + 255) / 256, 256, 0, stream>>>(W1, w1p);
    pack_w_kernel<C_HID, C_OUT><<<(C_HID * C_OUT + 255) / 256, 256, 0, stream>>>(W2, w2p);

    // layer 1: h1 = x @ W1 (MFMA, bf16 out) ; g = relu(agg(h1) + b1) -> bf16
    gemm_mfma_kernel<C_IN, C_HID><<<512, 256, 0, stream>>>(x16, w1p, h16, N);
    agg_kernel<C_HID, 4, true, false><<<(N + 3) / 4, 256, 0, stream>>>(
        h16, row_start, csr_src, dinv, b1, nullptr, nullptr, (void*)g16, N);

    // layer 2: h2 = g @ W2 (MFMA, bf16 out) ; out = LN(agg(h2) + b2) fused
    gemm_mfma_kernel<C_HID, C_OUT><<<512, 256, 0, stream>>>(g16, w2p, h16, N);
    agg_kernel<C_OUT, 2, false, true><<<(N + 3) / 4, 256, 0, stream>>>(
        h16, row_start, csr_src, dinv, b2, gamma, beta, (void*)out, N);
}

// Round 11
// 584.694 us; speedup vs baseline: 2.3955x; 1.0593x over previous
//
#include <hip/hip_runtime.h>
#include <hip/hip_bf16.h>

// ---------------- constants ----------------
#define C_IN  128
#define C_HID 256
#define C_OUT 128

typedef __attribute__((ext_vector_type(8))) short short8;
typedef __attribute__((ext_vector_type(4))) float f32x4;

static __device__ __forceinline__ unsigned short f2bf(float f) {
    __hip_bfloat16 h = __float2bfloat16(f);
    return __builtin_bit_cast(unsigned short, h);
}
static __device__ __forceinline__ float bf2f(unsigned short u) {
    unsigned int x = ((unsigned int)u) << 16;
    return __builtin_bit_cast(float, x);
}

// ---------------- CSR build ----------------
__global__ void count_kernel(const int* __restrict__ dst, int* __restrict__ cnt, int e, int n) {
    int i = blockIdx.x * blockDim.x + threadIdx.x;
    int stride = gridDim.x * blockDim.x;
    for (; i < e; i += stride) {
        unsigned d = (unsigned)dst[i];
        if (d < (unsigned)n) atomicAdd(&cnt[d], 1);
    }
}

__global__ void dinv_kernel(const int* __restrict__ cnt, float* __restrict__ dinv, int n) {
    int i = blockIdx.x * blockDim.x + threadIdx.x;
    if (i < n) dinv[i] = rsqrtf((float)(cnt[i] + 1));   // +1 self loop
}

__global__ __launch_bounds__(1024) void scan_kernel(const int* __restrict__ cnt,
                                                    int* __restrict__ row_start,
                                                    int* __restrict__ row_pos, int n) {
    __shared__ int wsum[16];
    __shared__ int s_carry;
    const int tid = threadIdx.x, lane = tid & 63, w = tid >> 6;
    if (tid == 0) s_carry = 0;
    __syncthreads();
    for (int base = 0; base < n; base += 1024) {
        int i = base + tid;
        int v = (i < n) ? cnt[i] : 0;
        int x = v;
        #pragma unroll
        for (int off = 1; off < 64; off <<= 1) {
            int y = __shfl_up(x, off);
            if (lane >= off) x += y;
        }
        if (lane == 63) wsum[w] = x;
        __syncthreads();
        int woff = 0, total = 0;
        #pragma unroll
        for (int j = 0; j < 16; ++j) {
            int s = wsum[j];
            if (j < w) woff += s;
            total += s;
        }
        int excl = s_carry + woff + (x - v);
        if (i < n) { row_start[i] = excl; row_pos[i] = excl; }
        __syncthreads();
        if (tid == 0) s_carry += total;
        __syncthreads();
    }
    if (tid == 0) row_start[n] = s_carry;
}

__global__ void fill_kernel(const int* __restrict__ src, const int* __restrict__ dst,
                            int* __restrict__ row_pos, int* __restrict__ csr_src, int e, int n) {
    int i = blockIdx.x * blockDim.x + threadIdx.x;
    int stride = gridDim.x * blockDim.x;
    for (; i < e; i += stride) {
        unsigned d = (unsigned)dst[i];
        unsigned s = (unsigned)src[i];
        if (d < (unsigned)n && s < (unsigned)n) {
            int p = atomicAdd(&row_pos[d], 1);
            // NT store: bypass per-XCD L2 so partial 64B lines merge once in MALL
            __builtin_nontemporal_store((int)s, &csr_src[p]);
        }
    }
}

// ---------------- f32 -> bf16 convert (vectorized) ----------------
__global__ void cvt_bf16_kernel(const float* __restrict__ in, unsigned short* __restrict__ out,
                                int n4) {   // n4 = total/4
    int i = blockIdx.x * blockDim.x + threadIdx.x;
    int stride = gridDim.x * blockDim.x;
    for (; i < n4; i += stride) {
        float4 v = *(const float4*)&in[(size_t)i * 4];
        ushort4 o;
        o.x = f2bf(v.x); o.y = f2bf(v.y); o.z = f2bf(v.z); o.w = f2bf(v.w);
        *(ushort4*)&out[(size_t)i * 4] = o;
    }
}

// ---------------- pack W [K][M] f32 -> MFMA-fragment-ordered bf16 ----------------
// flat o = ((ct*NKS + ks)*64 + lane)*8 + j  maps to  W[ks*32 + (lane>>4)*8 + j][ct*16 + (lane&15)]
template<int K, int M>
__global__ void pack_w_kernel(const float* __restrict__ W, unsigned short* __restrict__ Wp) {
    int o = blockIdx.x * 256 + threadIdx.x;
    if (o >= K * M) return;
    constexpr int NKS = K / 32;
    int j    = o & 7;
    int lane = (o >> 3) & 63;
    int rest = o >> 9;
    int ks = rest % NKS;
    int ct = rest / NKS;
    int k = ks * 32 + (lane >> 4) * 8 + j;
    int m = ct * 16 + (lane & 15);
    Wp[o] = f2bf(W[(size_t)k * M + m]);
}

// ---------------- MFMA GEMM: C[n,M] bf16 = A[n,K] bf16 @ W[K,M] (packed bf16) ----------------
template<int K, int M>
__global__ __launch_bounds__(256) void gemm_mfma_kernel(const unsigned short* __restrict__ A,
                                                        const unsigned short* __restrict__ Wp,
                                                        unsigned short* __restrict__ C, int n) {
    constexpr int NKS = K / 32;
    constexpr int NCT = M / 16;
    __shared__ unsigned short wl[K * M];            // 64 KB
    const int tid  = threadIdx.x;
    const int lane = tid & 63;
    const int wid  = tid >> 6;

    for (int i = tid; i < K * M / 8; i += 256)
        *(uint4*)&wl[(size_t)i * 8] = *(const uint4*)&Wp[(size_t)i * 8];
    __syncthreads();

    const int ntiles = (n + 63) / 64;
    for (int t = blockIdx.x; t < ntiles; t += gridDim.x) {
        const int row0 = t * 64 + wid * 16;
        int arow = row0 + (lane & 15);
        if (arow > n - 1) arow = n - 1;             // clamp (garbage rows masked at store)
        const unsigned short* ap = A + (size_t)arow * K + (lane >> 4) * 8;

        short8 afrag[NKS];
        #pragma unroll
        for (int ks = 0; ks < NKS; ++ks)
            afrag[ks] = *(const short8*)(ap + ks * 32);

        f32x4 acc[NCT] = {};
        #pragma unroll
        for (int ks = 0; ks < NKS; ++ks) {
            #pragma unroll
            for (int ct = 0; ct < NCT; ++ct) {
                short8 b = *(const short8*)&wl[((ct * NKS + ks) * 64 + lane) * 8];
                acc[ct] = __builtin_amdgcn_mfma_f32_16x16x32_bf16(afrag[ks], b, acc[ct], 0, 0, 0);
            }
        }

        // C/D layout: col = lane&15, row = (lane>>4)*4 + r   [verified m89]
        const int crow0 = row0 + (lane >> 4) * 4;
        const int ccol  = lane & 15;
        #pragma unroll
        for (int ct = 0; ct < NCT; ++ct) {
            #pragma unroll
            for (int r = 0; r < 4; ++r) {
                int row = crow0 + r;
                if (row < n)
                    C[(size_t)row * M + ct * 16 + ccol] = f2bf(acc[ct][r]);
            }
        }
    }
}

// ---------------- aggregation (bf16 H): out = bias + dinv[n]^2*H[n] + sum dinv[s]*dinv[n]*H[s]
// NPW nodes per wave (sub-wave of 64/NPW lanes each owns a node; 4 bf16 ch/lane).
// Requires CH == (64/NPW)*4. Edge loop unrolled x4 for memory-level parallelism.
template<int CH, int NPW, bool RELU, bool LN>
__global__ __launch_bounds__(256) void agg_kernel(const unsigned short* __restrict__ H,
                                                  const int* __restrict__ row_start,
                                                  const int* __restrict__ csr_src,
                                                  const float* __restrict__ dinv,
                                                  const float* __restrict__ bias,
                                                  const float* __restrict__ gamma,
                                                  const float* __restrict__ beta,
                                                  void* __restrict__ out_v, int n) {
    constexpr int SUBW = 64 / NPW;                  // lanes per node
    static_assert(CH == SUBW * 4, "layout");
    const int lane = threadIdx.x & 63;
    const int wid  = threadIdx.x >> 6;
    int node = blockIdx.x * 4 * NPW + wid * NPW + (NPW == 2 ? (lane >> 5) : 0);
    if (NPW == 1) node = __builtin_amdgcn_readfirstlane(node);
    if (node >= n) return;
    const int slane = lane & (SUBW - 1);
    const int c0 = slane * 4;

    const float dn = dinv[node];
    const int e0 = row_start[node], e1 = row_start[node + 1];

    float acc[4];
    {   // self loop
        float c = dn * dn;
        ushort4 h = *(const ushort4*)&H[(size_t)node * CH + c0];
        acc[0] = bf2f(h.x) * c; acc[1] = bf2f(h.y) * c;
        acc[2] = bf2f(h.z) * c; acc[3] = bf2f(h.w) * c;
    }
    int e = e0;
    for (; e + 4 <= e1; e += 4) {
        int s0 = csr_src[e + 0], s1 = csr_src[e + 1];
        int s2 = csr_src[e + 2], s3 = csr_src[e + 3];
        float w0 = dinv[s0] * dn, w1 = dinv[s1] * dn;
        float w2 = dinv[s2] * dn, w3 = dinv[s3] * dn;
        ushort4 h0 = *(const ushort4*)&H[(size_t)s0 * CH + c0];
        ushort4 h1 = *(const ushort4*)&H[(size_t)s1 * CH + c0];
        ushort4 h2 = *(const ushort4*)&H[(size_t)s2 * CH + c0];
        ushort4 h3 = *(const ushort4*)&H[(size_t)s3 * CH + c0];
        acc[0] += bf2f(h0.x) * w0; acc[1] += bf2f(h0.y) * w0;
        acc[2] += bf2f(h0.z) * w0; acc[3] += bf2f(h0.w) * w0;
        acc[0] += bf2f(h1.x) * w1; acc[1] += bf2f(h1.y) * w1;
        acc[2] += bf2f(h1.z) * w1; acc[3] += bf2f(h1.w) * w1;
        acc[0] += bf2f(h2.x) * w2; acc[1] += bf2f(h2.y) * w2;
        acc[2] += bf2f(h2.z) * w2; acc[3] += bf2f(h2.w) * w2;
        acc[0] += bf2f(h3.x) * w3; acc[1] += bf2f(h3.y) * w3;
        acc[2] += bf2f(h3.z) * w3; acc[3] += bf2f(h3.w) * w3;
    }
    for (; e < e1; ++e) {
        int s = csr_src[e];
        float c = dinv[s] * dn;
        ushort4 h = *(const ushort4*)&H[(size_t)s * CH + c0];
        acc[0] += bf2f(h.x) * c; acc[1] += bf2f(h.y) * c;
        acc[2] += bf2f(h.z) * c; acc[3] += bf2f(h.w) * c;
    }

    float4 bi = *(const float4*)&bias[c0];
    acc[0] += bi.x; acc[1] += bi.y; acc[2] += bi.z; acc[3] += bi.w;
    if (RELU) {
        #pragma unroll
        for (int v = 0; v < 4; ++v) acc[v] = fmaxf(acc[v], 0.f);
    }

    if (LN) {
        // fused LayerNorm over the sub-wave (SUBW lanes hold the full row)
        float s = acc[0] + acc[1] + acc[2] + acc[3];
        float ss = acc[0]*acc[0] + acc[1]*acc[1] + acc[2]*acc[2] + acc[3]*acc[3];
        #pragma unroll
        for (int off = SUBW / 2; off; off >>= 1) {
            s  += __shfl_xor(s, off);
            ss += __shfl_xor(ss, off);
        }
        float mu  = s * (1.f / (float)CH);
        float var = ss * (1.f / (float)CH) - mu * mu;
        float rstd = rsqrtf(var + 1e-5f);
        float4 g = *(const float4*)&gamma[c0];
        float4 b = *(const float4*)&beta[c0];
        f32x4 o;
        o[0] = (acc[0] - mu) * rstd * g.x + b.x;
        o[1] = (acc[1] - mu) * rstd * g.y + b.y;
        o[2] = (acc[2] - mu) * rstd * g.z + b.z;
        o[3] = (acc[3] - mu) * rstd * g.w + b.w;
        float* out = (float*)out_v;
        __builtin_nontemporal_store(o, (f32x4*)&out[(size_t)node * CH + c0]);
    } else {
        ushort4 o4;
        o4.x = f2bf(acc[0]); o4.y = f2bf(acc[1]);
        o4.z = f2bf(acc[2]); o4.w = f2bf(acc[3]);
        unsigned long long packed = __builtin_bit_cast(unsigned long long, o4);
        unsigned short* out = (unsigned short*)out_v;
        __builtin_nontemporal_store(packed,
            (unsigned long long*)&out[(size_t)node * CH + c0]);
    }
}

extern "C" void kernel_launch(void* const* d_in, const int* in_sizes, int n_in,
                              void* d_out, int out_size, void* d_ws, size_t ws_size,
                              hipStream_t stream) {
    const float* x     = (const float*)d_in[0];
    const int*   ei    = (const int*)d_in[1];     // int32 (harness: integer -> const int*)
    const float* W1    = (const float*)d_in[2];
    const float* b1    = (const float*)d_in[3];
    const float* W2    = (const float*)d_in[4];
    const float* b2    = (const float*)d_in[5];
    const float* gamma = (const float*)d_in[6];
    const float* beta  = (const float*)d_in[7];
    float* out = (float*)d_out;

    const int N = in_sizes[0] / C_IN;
    const int E = in_sizes[1] / 2;
    const int* src = ei;
    const int* dst = ei + E;

    // workspace layout (all bf16 intermediates)
    unsigned short* h16 = (unsigned short*)d_ws;            // N*256 (gemm1 out / gemm2 out reuse)
    unsigned short* g16 = h16 + (size_t)N * C_HID;          // N*256 (agg1 out, gemm2 in)
    unsigned short* x16 = g16 + (size_t)N * C_HID;          // N*128
    unsigned short* w1p = x16 + (size_t)N * C_IN;           // 128*256
    unsigned short* w2p = w1p + C_IN * C_HID;               // 256*128
    float* dinv  = (float*)(w2p + C_HID * C_OUT);           // N
    int*   cnt   = (int*)(dinv + N);                        // N
    int*   row_start = cnt + N;                             // N+1 (pad 4)
    int*   row_pos   = row_start + N + 4;                   // N
    int*   csr_src   = row_pos + N;                         // E

    hipMemsetAsync(cnt, 0, (size_t)N * sizeof(int), stream);

    count_kernel<<<2048, 256, 0, stream>>>(dst, cnt, E, N);
    dinv_kernel<<<(N + 255) / 256, 256, 0, stream>>>(cnt, dinv, N);
    scan_kernel<<<1, 1024, 0, stream>>>(cnt, row_start, row_pos, N);
    fill_kernel<<<2048, 256, 0, stream>>>(src, dst, row_pos, csr_src, E, N);

    // input conversions / weight packing
    cvt_bf16_kernel<<<2048, 256, 0, stream>>>(x, x16, N * C_IN / 4);
    pack_w_kernel<C_IN, C_HID><<<(C_IN * C_HID + 255) / 256, 256, 0, stream>>>(W1, w1p);
    pack_w_kernel<C_HID, C_OUT><<<(C_HID * C_OUT + 255) / 256, 256, 0, stream>>>(W2, w2p);

    // layer 1: h1 = x @ W1 (MFMA, bf16 out) ; g = relu(agg(h1) + b1) -> bf16
    gemm_mfma_kernel<C_IN, C_HID><<<512, 256, 0, stream>>>(x16, w1p, h16, N);
    agg_kernel<C_HID, 1, true, false><<<(N + 3) / 4, 256, 0, stream>>>(
        h16, row_start, csr_src, dinv, b1, nullptr, nullptr, (void*)g16, N);

    // layer 2: h2 = g @ W2 (MFMA, bf16 out) ; out = LN(agg(h2) + b2) fused
    gemm_mfma_kernel<C_HID, C_OUT><<<512, 256, 0, stream>>>(g16, w2p, h16, N);
    agg_kernel<C_OUT, 2, false, true><<<(N + 7) / 8, 256, 0, stream>>>(
        h16, row_start, csr_src, dinv, b2, gamma, beta, (void*)out, N);
}

// Round 12
// 457.000 us; speedup vs baseline: 3.0648x; 1.2794x over previous
//
#include <hip/hip_runtime.h>
#include <hip/hip_bf16.h>

// ---------------- constants ----------------
#define C_IN  128
#define C_HID 256
#define C_OUT 128

typedef __attribute__((ext_vector_type(8))) short short8;
typedef __attribute__((ext_vector_type(4))) float f32x4;

static __device__ __forceinline__ unsigned short f2bf(float f) {
    __hip_bfloat16 h = __float2bfloat16(f);
    return __builtin_bit_cast(unsigned short, h);
}
static __device__ __forceinline__ float bf2f(unsigned short u) {
    unsigned int x = ((unsigned int)u) << 16;
    return __builtin_bit_cast(float, x);
}

// ---------------- CSR build ----------------
// count + per-edge rank (rank = position of edge within its dst's segment)
__global__ void count_kernel(const int* __restrict__ dst, int* __restrict__ cnt,
                             int* __restrict__ rank, int e, int n) {
    int i = blockIdx.x * blockDim.x + threadIdx.x;
    int stride = gridDim.x * blockDim.x;
    for (; i < e; i += stride) {
        unsigned d = (unsigned)dst[i];
        int r = 0;
        if (d < (unsigned)n) r = atomicAdd(&cnt[d], 1);
        rank[i] = r;
    }
}

__global__ void dinv_kernel(const int* __restrict__ cnt, float* __restrict__ dinv, int n) {
    int i = blockIdx.x * blockDim.x + threadIdx.x;
    if (i < n) dinv[i] = rsqrtf((float)(cnt[i] + 1));   // +1 self loop
}

__global__ __launch_bounds__(1024) void scan_kernel(const int* __restrict__ cnt,
                                                    int* __restrict__ row_start, int n) {
    __shared__ int wsum[16];
    __shared__ int s_carry;
    const int tid = threadIdx.x, lane = tid & 63, w = tid >> 6;
    if (tid == 0) s_carry = 0;
    __syncthreads();
    for (int base = 0; base < n; base += 1024) {
        int i = base + tid;
        int v = (i < n) ? cnt[i] : 0;
        int x = v;
        #pragma unroll
        for (int off = 1; off < 64; off <<= 1) {
            int y = __shfl_up(x, off);
            if (lane >= off) x += y;
        }
        if (lane == 63) wsum[w] = x;
        __syncthreads();
        int woff = 0, total = 0;
        #pragma unroll
        for (int j = 0; j < 16; ++j) {
            int s = wsum[j];
            if (j < w) woff += s;
            total += s;
        }
        int excl = s_carry + woff + (x - v);
        if (i < n) row_start[i] = excl;
        __syncthreads();
        if (tid == 0) s_carry += total;
        __syncthreads();
    }
    if (tid == 0) row_start[n] = s_carry;
}

// atomic-free scatter: p = row_start[d] + rank[i]
__global__ void fill_kernel(const int* __restrict__ src, const int* __restrict__ dst,
                            const int* __restrict__ rank, const int* __restrict__ row_start,
                            int* __restrict__ csr_src, int e, int n) {
    int i = blockIdx.x * blockDim.x + threadIdx.x;
    int stride = gridDim.x * blockDim.x;
    for (; i < e; i += stride) {
        unsigned d = (unsigned)dst[i];
        unsigned s = (unsigned)src[i];
        if (d < (unsigned)n && s < (unsigned)n) {
            int p = row_start[d] + rank[i];
            csr_src[p] = (int)s;
        }
    }
}

// ---------------- f32 -> bf16 convert (vectorized) ----------------
__global__ void cvt_bf16_kernel(const float* __restrict__ in, unsigned short* __restrict__ out,
                                int n4) {   // n4 = total/4
    int i = blockIdx.x * blockDim.x + threadIdx.x;
    int stride = gridDim.x * blockDim.x;
    for (; i < n4; i += stride) {
        float4 v = *(const float4*)&in[(size_t)i * 4];
        ushort4 o;
        o.x = f2bf(v.x); o.y = f2bf(v.y); o.z = f2bf(v.z); o.w = f2bf(v.w);
        *(ushort4*)&out[(size_t)i * 4] = o;
    }
}

// ---------------- pack W [K][M] f32 -> MFMA-fragment-ordered bf16 ----------------
// flat o = ((ct*NKS + ks)*64 + lane)*8 + j  maps to  W[ks*32 + (lane>>4)*8 + j][ct*16 + (lane&15)]
template<int K, int M>
__global__ void pack_w_kernel(const float* __restrict__ W, unsigned short* __restrict__ Wp) {
    int o = blockIdx.x * 256 + threadIdx.x;
    if (o >= K * M) return;
    constexpr int NKS = K / 32;
    int j    = o & 7;
    int lane = (o >> 3) & 63;
    int rest = o >> 9;
    int ks = rest % NKS;
    int ct = rest / NKS;
    int k = ks * 32 + (lane >> 4) * 8 + j;
    int m = ct * 16 + (lane & 15);
    Wp[o] = f2bf(W[(size_t)k * M + m]);
}

// ---------------- MFMA GEMM: C[n,M] bf16 = A[n,K] bf16 @ W[K,M] (packed bf16) ----------------
template<int K, int M>
__global__ __launch_bounds__(256) void gemm_mfma_kernel(const unsigned short* __restrict__ A,
                                                        const unsigned short* __restrict__ Wp,
                                                        unsigned short* __restrict__ C, int n) {
    constexpr int NKS = K / 32;
    constexpr int NCT = M / 16;
    __shared__ unsigned short wl[K * M];            // 64 KB
    const int tid  = threadIdx.x;
    const int lane = tid & 63;
    const int wid  = tid >> 6;

    for (int i = tid; i < K * M / 8; i += 256)
        *(uint4*)&wl[(size_t)i * 8] = *(const uint4*)&Wp[(size_t)i * 8];
    __syncthreads();

    const int ntiles = (n + 63) / 64;
    for (int t = blockIdx.x; t < ntiles; t += gridDim.x) {
        const int row0 = t * 64 + wid * 16;
        int arow = row0 + (lane & 15);
        if (arow > n - 1) arow = n - 1;             // clamp (garbage rows masked at store)
        const unsigned short* ap = A + (size_t)arow * K + (lane >> 4) * 8;

        short8 afrag[NKS];
        #pragma unroll
        for (int ks = 0; ks < NKS; ++ks)
            afrag[ks] = *(const short8*)(ap + ks * 32);

        f32x4 acc[NCT] = {};
        #pragma unroll
        for (int ks = 0; ks < NKS; ++ks) {
            #pragma unroll
            for (int ct = 0; ct < NCT; ++ct) {
                short8 b = *(const short8*)&wl[((ct * NKS + ks) * 64 + lane) * 8];
                acc[ct] = __builtin_amdgcn_mfma_f32_16x16x32_bf16(afrag[ks], b, acc[ct], 0, 0, 0);
            }
        }

        // C/D layout: col = lane&15, row = (lane>>4)*4 + r   [verified m89]
        const int crow0 = row0 + (lane >> 4) * 4;
        const int ccol  = lane & 15;
        #pragma unroll
        for (int ct = 0; ct < NCT; ++ct) {
            #pragma unroll
            for (int r = 0; r < 4; ++r) {
                int row = crow0 + r;
                if (row < n)
                    C[(size_t)row * M + ct * 16 + ccol] = f2bf(acc[ct][r]);
            }
        }
    }
}

// ---------------- aggregation (bf16 H): out = bias + dinv[n]^2*H[n] + sum dinv[s]*dinv[n]*H[s]
// NPW nodes per wave (sub-wave of 64/NPW lanes each owns a node; 4 bf16 ch/lane).
// Requires CH == (64/NPW)*4. Edge loop unrolled x4 for memory-level parallelism.
template<int CH, int NPW, bool RELU, bool LN>
__global__ __launch_bounds__(256) void agg_kernel(const unsigned short* __restrict__ H,
                                                  const int* __restrict__ row_start,
                                                  const int* __restrict__ csr_src,
                                                  const float* __restrict__ dinv,
                                                  const float* __restrict__ bias,
                                                  const float* __restrict__ gamma,
                                                  const float* __restrict__ beta,
                                                  void* __restrict__ out_v, int n) {
    constexpr int SUBW = 64 / NPW;                  // lanes per node
    static_assert(CH == SUBW * 4, "layout");
    const int lane = threadIdx.x & 63;
    const int wid  = threadIdx.x >> 6;
    int node = blockIdx.x * 4 * NPW + wid * NPW + (NPW == 2 ? (lane >> 5) : 0);
    if (NPW == 1) node = __builtin_amdgcn_readfirstlane(node);
    if (node >= n) return;
    const int slane = lane & (SUBW - 1);
    const int c0 = slane * 4;

    const float dn = dinv[node];
    const int e0 = row_start[node], e1 = row_start[node + 1];

    float acc[4];
    {   // self loop
        float c = dn * dn;
        ushort4 h = *(const ushort4*)&H[(size_t)node * CH + c0];
        acc[0] = bf2f(h.x) * c; acc[1] = bf2f(h.y) * c;
        acc[2] = bf2f(h.z) * c; acc[3] = bf2f(h.w) * c;
    }
    int e = e0;
    for (; e + 4 <= e1; e += 4) {
        int s0 = csr_src[e + 0], s1 = csr_src[e + 1];
        int s2 = csr_src[e + 2], s3 = csr_src[e + 3];
        float w0 = dinv[s0] * dn, w1 = dinv[s1] * dn;
        float w2 = dinv[s2] * dn, w3 = dinv[s3] * dn;
        ushort4 h0 = *(const ushort4*)&H[(size_t)s0 * CH + c0];
        ushort4 h1 = *(const ushort4*)&H[(size_t)s1 * CH + c0];
        ushort4 h2 = *(const ushort4*)&H[(size_t)s2 * CH + c0];
        ushort4 h3 = *(const ushort4*)&H[(size_t)s3 * CH + c0];
        acc[0] += bf2f(h0.x) * w0; acc[1] += bf2f(h0.y) * w0;
        acc[2] += bf2f(h0.z) * w0; acc[3] += bf2f(h0.w) * w0;
        acc[0] += bf2f(h1.x) * w1; acc[1] += bf2f(h1.y) * w1;
        acc[2] += bf2f(h1.z) * w1; acc[3] += bf2f(h1.w) * w1;
        acc[0] += bf2f(h2.x) * w2; acc[1] += bf2f(h2.y) * w2;
        acc[2] += bf2f(h2.z) * w2; acc[3] += bf2f(h2.w) * w2;
        acc[0] += bf2f(h3.x) * w3; acc[1] += bf2f(h3.y) * w3;
        acc[2] += bf2f(h3.z) * w3; acc[3] += bf2f(h3.w) * w3;
    }
    for (; e < e1; ++e) {
        int s = csr_src[e];
        float c = dinv[s] * dn;
        ushort4 h = *(const ushort4*)&H[(size_t)s * CH + c0];
        acc[0] += bf2f(h.x) * c; acc[1] += bf2f(h.y) * c;
        acc[2] += bf2f(h.z) * c; acc[3] += bf2f(h.w) * c;
    }

    float4 bi = *(const float4*)&bias[c0];
    acc[0] += bi.x; acc[1] += bi.y; acc[2] += bi.z; acc[3] += bi.w;
    if (RELU) {
        #pragma unroll
        for (int v = 0; v < 4; ++v) acc[v] = fmaxf(acc[v], 0.f);
    }

    if (LN) {
        // fused LayerNorm over the sub-wave (SUBW lanes hold the full row)
        float s = acc[0] + acc[1] + acc[2] + acc[3];
        float ss = acc[0]*acc[0] + acc[1]*acc[1] + acc[2]*acc[2] + acc[3]*acc[3];
        #pragma unroll
        for (int off = SUBW / 2; off; off >>= 1) {
            s  += __shfl_xor(s, off);
            ss += __shfl_xor(ss, off);
        }
        float mu  = s * (1.f / (float)CH);
        float var = ss * (1.f / (float)CH) - mu * mu;
        float rstd = rsqrtf(var + 1e-5f);
        float4 g = *(const float4*)&gamma[c0];
        float4 b = *(const float4*)&beta[c0];
        f32x4 o;
        o[0] = (acc[0] - mu) * rstd * g.x + b.x;
        o[1] = (acc[1] - mu) * rstd * g.y + b.y;
        o[2] = (acc[2] - mu) * rstd * g.z + b.z;
        o[3] = (acc[3] - mu) * rstd * g.w + b.w;
        float* out = (float*)out_v;
        __builtin_nontemporal_store(o, (f32x4*)&out[(size_t)node * CH + c0]);  // final out: write-only
    } else {
        ushort4 o4;
        o4.x = f2bf(acc[0]); o4.y = f2bf(acc[1]);
        o4.z = f2bf(acc[2]); o4.w = f2bf(acc[3]);
        unsigned short* out = (unsigned short*)out_v;
        *(ushort4*)&out[(size_t)node * CH + c0] = o4;   // plain store: g16 is re-read by gemm2
    }
}

extern "C" void kernel_launch(void* const* d_in, const int* in_sizes, int n_in,
                              void* d_out, int out_size, void* d_ws, size_t ws_size,
                              hipStream_t stream) {
    const float* x     = (const float*)d_in[0];
    const int*   ei    = (const int*)d_in[1];     // int32 (harness: integer -> const int*)
    const float* W1    = (const float*)d_in[2];
    const float* b1    = (const float*)d_in[3];
    const float* W2    = (const float*)d_in[4];
    const float* b2    = (const float*)d_in[5];
    const float* gamma = (const float*)d_in[6];
    const float* beta  = (const float*)d_in[7];
    float* out = (float*)d_out;

    const int N = in_sizes[0] / C_IN;
    const int E = in_sizes[1] / 2;
    const int* src = ei;
    const int* dst = ei + E;

    // workspace layout (all bf16 intermediates)
    unsigned short* h16 = (unsigned short*)d_ws;            // N*256 (gemm1 out / gemm2 out reuse)
    unsigned short* g16 = h16 + (size_t)N * C_HID;          // N*256 (agg1 out, gemm2 in)
    unsigned short* x16 = g16 + (size_t)N * C_HID;          // N*128
    unsigned short* w1p = x16 + (size_t)N * C_IN;           // 128*256
    unsigned short* w2p = w1p + C_IN * C_HID;               // 256*128
    float* dinv  = (float*)(w2p + C_HID * C_OUT);           // N
    int*   cnt   = (int*)(dinv + N);                        // N
    int*   row_start = cnt + N;                             // N+1 (pad 4)
    int*   rank      = row_start + N + 4;                   // E
    int*   csr_src   = rank + E;                            // E

    hipMemsetAsync(cnt, 0, (size_t)N * sizeof(int), stream);

    count_kernel<<<2048, 256, 0, stream>>>(dst, cnt, rank, E, N);
    dinv_kernel<<<(N + 255) / 256, 256, 0, stream>>>(cnt, dinv, N);
    scan_kernel<<<1, 1024, 0, stream>>>(cnt, row_start, N);
    fill_kernel<<<2048, 256, 0, stream>>>(src, dst, rank, row_start, csr_src, E, N);

    // input conversions / weight packing
    cvt_bf16_kernel<<<2048, 256, 0, stream>>>(x, x16, N * C_IN / 4);
    pack_w_kernel<C_IN, C_HID><<<(C_IN * C_HID + 255) / 256, 256, 0, stream>>>(W1, w1p);
    pack_w_kernel<C_HID, C_OUT><<<(C_HID * C_OUT + 255) / 256, 256, 0, stream>>>(W2, w2p);

    // layer 1: h1 = x @ W1 (MFMA, bf16 out) ; g = relu(agg(h1) + b1) -> bf16
    gemm_mfma_kernel<C_IN, C_HID><<<512, 256, 0, stream>>>(x16, w1p, h16, N);
    agg_kernel<C_HID, 1, true, false><<<(N + 3) / 4, 256, 0, stream>>>(
        h16, row_start, csr_src, dinv, b1, nullptr, nullptr, (void*)g16, N);

    // layer 2: h2 = g @ W2 (MFMA, bf16 out) ; out = LN(agg(h2) + b2) fused
    gemm_mfma_kernel<C_HID, C_OUT><<<512, 256, 0, stream>>>(g16, w2p, h16, N);
    agg_kernel<C_OUT, 2, false, true><<<(N + 7) / 8, 256, 0, stream>>>(
        h16, row_start, csr_src, dinv, b2, gamma, beta, (void*)out, N);
}

// Round 14
// 409.572 us; speedup vs baseline: 3.4197x; 1.1158x over previous
//
#include <hip/hip_runtime.h>
#include <hip/hip_bf16.h>

// ---------------- constants ----------------
#define C_IN  128
#define C_HID 256
#define C_OUT 128

typedef __attribute__((ext_vector_type(8))) short short8;
typedef __attribute__((ext_vector_type(4))) float f32x4;

static __device__ __forceinline__ unsigned short f2bf(float f) {
    __hip_bfloat16 h = __float2bfloat16(f);
    return __builtin_bit_cast(unsigned short, h);
}
static __device__ __forceinline__ float bf2f(unsigned short u) {
    unsigned int x = ((unsigned int)u) << 16;
    return __builtin_bit_cast(float, x);
}

// ---------------- fused prep: count+rank | cvt x->bf16 | pack W1 | pack W2 ----------------
static __device__ __forceinline__ void pack_one(const float* __restrict__ W,
                                                unsigned short* __restrict__ Wp,
                                                int o, int NKS, int M) {
    int j    = o & 7;
    int lane = (o >> 3) & 63;
    int rest = o >> 9;
    int ks = rest % NKS;
    int ct = rest / NKS;
    int k = ks * 32 + (lane >> 4) * 8 + j;
    int m = ct * 16 + (lane & 15);
    Wp[o] = f2bf(W[(size_t)k * M + m]);
}

#define CVT_BLOCKS   512
#define PACK_BLOCKS  128     // 32768 / 256
#define COUNT_BLOCKS 1024
#define PREP_BLOCKS  (CVT_BLOCKS + 2 * PACK_BLOCKS + COUNT_BLOCKS)

__global__ __launch_bounds__(256) void prep_kernel(const float* __restrict__ x,
                                                   unsigned short* __restrict__ x16, int n4,
                                                   const float* __restrict__ W1,
                                                   unsigned short* __restrict__ w1p,
                                                   const float* __restrict__ W2,
                                                   unsigned short* __restrict__ w2p,
                                                   const int* __restrict__ dst,
                                                   int* __restrict__ cnt,
                                                   int* __restrict__ rank, int e, int n) {
    const int b = blockIdx.x, tid = threadIdx.x;
    if (b < CVT_BLOCKS) {
        for (int i = b * 256 + tid; i < n4; i += CVT_BLOCKS * 256) {
            float4 v = *(const float4*)&x[(size_t)i * 4];
            ushort4 o;
            o.x = f2bf(v.x); o.y = f2bf(v.y); o.z = f2bf(v.z); o.w = f2bf(v.w);
            *(ushort4*)&x16[(size_t)i * 4] = o;
        }
    } else if (b < CVT_BLOCKS + PACK_BLOCKS) {
        pack_one(W1, w1p, (b - CVT_BLOCKS) * 256 + tid, C_IN / 32, C_HID);
    } else if (b < CVT_BLOCKS + 2 * PACK_BLOCKS) {
        pack_one(W2, w2p, (b - CVT_BLOCKS - PACK_BLOCKS) * 256 + tid, C_HID / 32, C_OUT);
    } else {
        const int cb = b - CVT_BLOCKS - 2 * PACK_BLOCKS;
        for (int i = cb * 256 + tid; i < e; i += COUNT_BLOCKS * 256) {
            unsigned d = (unsigned)dst[i];
            int r = 0;
            if (d < (unsigned)n) r = atomicAdd(&cnt[d], 1);
            rank[i] = r;
        }
    }
}

// ---------------- scan (+ dinv folded in) ----------------
__global__ __launch_bounds__(1024) void scan_kernel(const int* __restrict__ cnt,
                                                    int* __restrict__ row_start,
                                                    float* __restrict__ dinv, int n) {
    __shared__ int wsum[16];
    __shared__ int s_carry;
    const int tid = threadIdx.x, lane = tid & 63, w = tid >> 6;
    if (tid == 0) s_carry = 0;
    __syncthreads();
    for (int base = 0; base < n; base += 1024) {
        int i = base + tid;
        int v = (i < n) ? cnt[i] : 0;
        if (i < n) dinv[i] = rsqrtf((float)(v + 1));    // +1 self loop
        int x = v;
        #pragma unroll
        for (int off = 1; off < 64; off <<= 1) {
            int y = __shfl_up(x, off);
            if (lane >= off) x += y;
        }
        if (lane == 63) wsum[w] = x;
        __syncthreads();
        int woff = 0, total = 0;
        #pragma unroll
        for (int j = 0; j < 16; ++j) {
            int s = wsum[j];
            if (j < w) woff += s;
            total += s;
        }
        int excl = s_carry + woff + (x - v);
        if (i < n) row_start[i] = excl;
        __syncthreads();
        if (tid == 0) s_carry += total;
        __syncthreads();
    }
    if (tid == 0) row_start[n] = s_carry;
}

// atomic-free scatter: p = row_start[d] + rank[i]
__global__ void fill_kernel(const int* __restrict__ src, const int* __restrict__ dst,
                            const int* __restrict__ rank, const int* __restrict__ row_start,
                            int* __restrict__ csr_src, int e, int n) {
    int i = blockIdx.x * blockDim.x + threadIdx.x;
    int stride = gridDim.x * blockDim.x;
    for (; i < e; i += stride) {
        unsigned d = (unsigned)dst[i];
        unsigned s = (unsigned)src[i];
        if (d < (unsigned)n && s < (unsigned)n) {
            int p = row_start[d] + rank[i];
            csr_src[p] = (int)s;
        }
    }
}

// ---------------- MFMA GEMM: C[n,M] bf16 = A[n,K] bf16 @ W[K,M] (packed bf16) ----------------
// Optional fused epilogue: relu(v + bias[col])
template<int K, int M, bool BIASRELU>
__global__ __launch_bounds__(256) void gemm_mfma_kernel(const unsigned short* __restrict__ A,
                                                        const unsigned short* __restrict__ Wp,
                                                        unsigned short* __restrict__ C,
                                                        const float* __restrict__ bias, int n) {
    constexpr int NKS = K / 32;
    constexpr int NCT = M / 16;
    __shared__ unsigned short wl[K * M];            // 64 KB
    const int tid  = threadIdx.x;
    const int lane = tid & 63;
    const int wid  = tid >> 6;

    for (int i = tid; i < K * M / 8; i += 256)
        *(uint4*)&wl[(size_t)i * 8] = *(const uint4*)&Wp[(size_t)i * 8];
    __syncthreads();

    const int ntiles = (n + 63) / 64;
    for (int t = blockIdx.x; t < ntiles; t += gridDim.x) {
        const int row0 = t * 64 + wid * 16;
        int arow = row0 + (lane & 15);
        if (arow > n - 1) arow = n - 1;             // clamp (garbage rows masked at store)
        const unsigned short* ap = A + (size_t)arow * K + (lane >> 4) * 8;

        short8 afrag[NKS];
        #pragma unroll
        for (int ks = 0; ks < NKS; ++ks)
            afrag[ks] = *(const short8*)(ap + ks * 32);

        f32x4 acc[NCT] = {};
        #pragma unroll
        for (int ks = 0; ks < NKS; ++ks) {
            #pragma unroll
            for (int ct = 0; ct < NCT; ++ct) {
                short8 b = *(const short8*)&wl[((ct * NKS + ks) * 64 + lane) * 8];
                acc[ct] = __builtin_amdgcn_mfma_f32_16x16x32_bf16(afrag[ks], b, acc[ct], 0, 0, 0);
            }
        }

        // C/D layout: col = lane&15, row = (lane>>4)*4 + r   [verified m89]
        const int crow0 = row0 + (lane >> 4) * 4;
        const int ccol  = lane & 15;
        #pragma unroll
        for (int ct = 0; ct < NCT; ++ct) {
            float bv = BIASRELU ? bias[ct * 16 + ccol] : 0.f;
            #pragma unroll
            for (int r = 0; r < 4; ++r) {
                int row = crow0 + r;
                if (row < n) {
                    float v = acc[ct][r];
                    if (BIASRELU) v = fmaxf(v + bv, 0.f);
                    C[(size_t)row * M + ct * 16 + ccol] = f2bf(v);
                }
            }
        }
    }
}

// ---------------- aggregation (bf16 H): out = [bias +] dinv[n]^2*H[n] + sum dinv[s]*dinv[n]*H[s]
// NPW nodes per wave (sub-wave of 64/NPW lanes each owns a node; 4 bf16 ch/lane).
// Edge loop unrolled x4 for memory-level parallelism.
template<int CH, int NPW, bool HASBIAS, bool RELU, bool LN>
__global__ __launch_bounds__(256) void agg_kernel(const unsigned short* __restrict__ H,
                                                  const int* __restrict__ row_start,
                                                  const int* __restrict__ csr_src,
                                                  const float* __restrict__ dinv,
                                                  const float* __restrict__ bias,
                                                  const float* __restrict__ gamma,
                                                  const float* __restrict__ beta,
                                                  void* __restrict__ out_v, int n) {
    constexpr int SUBW = 64 / NPW;                  // lanes per node
    static_assert(CH == SUBW * 4, "layout");
    const int lane = threadIdx.x & 63;
    const int wid  = threadIdx.x >> 6;
    int node = blockIdx.x * 4 * NPW + wid * NPW + (NPW == 2 ? (lane >> 5) : 0);
    if (NPW == 1) node = __builtin_amdgcn_readfirstlane(node);
    if (node >= n) return;
    const int slane = lane & (SUBW - 1);
    const int c0 = slane * 4;

    const float dn = dinv[node];
    const int e0 = row_start[node], e1 = row_start[node + 1];

    float acc[4];
    {   // self loop
        float c = dn * dn;
        ushort4 h = *(const ushort4*)&H[(size_t)node * CH + c0];
        acc[0] = bf2f(h.x) * c; acc[1] = bf2f(h.y) * c;
        acc[2] = bf2f(h.z) * c; acc[3] = bf2f(h.w) * c;
    }
    int e = e0;
    for (; e + 4 <= e1; e += 4) {
        int s0 = csr_src[e + 0], s1 = csr_src[e + 1];
        int s2 = csr_src[e + 2], s3 = csr_src[e + 3];
        float w0 = dinv[s0] * dn, w1 = dinv[s1] * dn;
        float w2 = dinv[s2] * dn, w3 = dinv[s3] * dn;
        ushort4 h0 = *(const ushort4*)&H[(size_t)s0 * CH + c0];
        ushort4 h1 = *(const ushort4*)&H[(size_t)s1 * CH + c0];
        ushort4 h2 = *(const ushort4*)&H[(size_t)s2 * CH + c0];
        ushort4 h3 = *(const ushort4*)&H[(size_t)s3 * CH + c0];
        acc[0] += bf2f(h0.x) * w0; acc[1] += bf2f(h0.y) * w0;
        acc[2] += bf2f(h0.z) * w0; acc[3] += bf2f(h0.w) * w0;
        acc[0] += bf2f(h1.x) * w1; acc[1] += bf2f(h1.y) * w1;
        acc[2] += bf2f(h1.z) * w1; acc[3] += bf2f(h1.w) * w1;
        acc[0] += bf2f(h2.x) * w2; acc[1] += bf2f(h2.y) * w2;
        acc[2] += bf2f(h2.z) * w2; acc[3] += bf2f(h2.w) * w2;
        acc[0] += bf2f(h3.x) * w3; acc[1] += bf2f(h3.y) * w3;
        acc[2] += bf2f(h3.z) * w3; acc[3] += bf2f(h3.w) * w3;
    }
    for (; e < e1; ++e) {
        int s = csr_src[e];
        float c = dinv[s] * dn;
        ushort4 h = *(const ushort4*)&H[(size_t)s * CH + c0];
        acc[0] += bf2f(h.x) * c; acc[1] += bf2f(h.y) * c;
        acc[2] += bf2f(h.z) * c; acc[3] += bf2f(h.w) * c;
    }

    if (HASBIAS) {
        float4 bi = *(const float4*)&bias[c0];
        acc[0] += bi.x; acc[1] += bi.y; acc[2] += bi.z; acc[3] += bi.w;
    }
    if (RELU) {
        #pragma unroll
        for (int v = 0; v < 4; ++v) acc[v] = fmaxf(acc[v], 0.f);
    }

    if (LN) {
        // fused LayerNorm over the sub-wave (SUBW lanes hold the full row)
        float s = acc[0] + acc[1] + acc[2] + acc[3];
        float ss = acc[0]*acc[0] + acc[1]*acc[1] + acc[2]*acc[2] + acc[3]*acc[3];
        #pragma unroll
        for (int off = SUBW / 2; off; off >>= 1) {
            s  += __shfl_xor(s, off);
            ss += __shfl_xor(ss, off);
        }
        float mu  = s * (1.f / (float)CH);
        float var = ss * (1.f / (float)CH) - mu * mu;
        float rstd = rsqrtf(var + 1e-5f);
        float4 g = *(const float4*)&gamma[c0];
        float4 b = *(const float4*)&beta[c0];
        f32x4 o;
        o[0] = (acc[0] - mu) * rstd * g.x + b.x;
        o[1] = (acc[1] - mu) * rstd * g.y + b.y;
        o[2] = (acc[2] - mu) * rstd * g.z + b.z;
        o[3] = (acc[3] - mu) * rstd * g.w + b.w;
        float* out = (float*)out_v;
        __builtin_nontemporal_store(o, (f32x4*)&out[(size_t)node * CH + c0]);  // final out: write-only
    } else {
        ushort4 o4;
        o4.x = f2bf(acc[0]); o4.y = f2bf(acc[1]);
        o4.z = f2bf(acc[2]); o4.w = f2bf(acc[3]);
        unsigned short* out = (unsigned short*)out_v;
        *(ushort4*)&out[(size_t)node * CH + c0] = o4;   // plain store: re-read by next gemm
    }
}

extern "C" void kernel_launch(void* const* d_in, const int* in_sizes, int n_in,
                              void* d_out, int out_size, void* d_ws, size_t ws_size,
                              hipStream_t stream) {
    const float* x     = (const float*)d_in[0];
    const int*   ei    = (const int*)d_in[1];     // int32 (harness: integer -> const int*)
    const float* W1    = (const float*)d_in[2];
    const float* b1    = (const float*)d_in[3];
    const float* W2    = (const float*)d_in[4];
    const float* b2    = (const float*)d_in[5];
    const float* gamma = (const float*)d_in[6];
    const float* beta  = (const float*)d_in[7];
    float* out = (float*)d_out;

    const int N = in_sizes[0] / C_IN;
    const int E = in_sizes[1] / 2;
    const int* src = ei;
    const int* dst = ei + E;

    // workspace layout
    unsigned short* x16 = (unsigned short*)d_ws;            // N*128 (x in bf16)
    unsigned short* xa  = x16 + (size_t)N * C_IN;           // N*128 (S·x)
    unsigned short* g16 = xa + (size_t)N * C_IN;            // N*256 (relu(S·x@W1+b1))
    unsigned short* h2  = g16 + (size_t)N * C_HID;          // N*128 (g@W2)
    unsigned short* w1p = h2 + (size_t)N * C_OUT;           // 128*256
    unsigned short* w2p = w1p + C_IN * C_HID;               // 256*128
    float* dinv  = (float*)(w2p + C_HID * C_OUT);           // N
    int*   cnt   = (int*)(dinv + N);                        // N
    int*   row_start = cnt + N;                             // N+1 (pad 4)
    int*   rank      = row_start + N + 4;                   // E
    int*   csr_src   = rank + E;                            // E

    hipMemsetAsync(cnt, 0, (size_t)N * sizeof(int), stream);

    // fused: count+rank | cvt x | pack W1 | pack W2
    prep_kernel<<<PREP_BLOCKS, 256, 0, stream>>>(x, x16, N * C_IN / 4,
                                                 W1, w1p, W2, w2p,
                                                 dst, cnt, rank, E, N);
    scan_kernel<<<1, 1024, 0, stream>>>(cnt, row_start, dinv, N);
    fill_kernel<<<2048, 256, 0, stream>>>(src, dst, rank, row_start, csr_src, E, N);

    // layer 1 (reordered by linearity): xa = S·x ; g = relu(xa@W1 + b1)
    agg_kernel<C_IN, 2, false, false, false><<<(N + 7) / 8, 256, 0, stream>>>(
        x16, row_start, csr_src, dinv, nullptr, nullptr, nullptr, (void*)xa, N);
    gemm_mfma_kernel<C_IN, C_HID, true><<<512, 256, 0, stream>>>(xa, w1p, g16, b1, N);

    // layer 2: h2 = g@W2 ; out = LN(S·h2 + b2)
    gemm_mfma_kernel<C_HID, C_OUT, false><<<512, 256, 0, stream>>>(g16, w2p, h2, nullptr, N);
    agg_kernel<C_OUT, 2, true, false, true><<<(N + 7) / 8, 256, 0, stream>>>(
        h2, row_start, csr_src, dinv, b2, gamma, beta, (void*)out, N);
}

// Round 15
// 309.748 us; speedup vs baseline: 4.5218x; 1.3223x over previous
//
#include <hip/hip_runtime.h>
#include <hip/hip_bf16.h>

// ---------------- constants ----------------
#define C_IN  128
#define C_HID 256
#define C_OUT 128

typedef __attribute__((ext_vector_type(8))) short short8;
typedef __attribute__((ext_vector_type(4))) float f32x4;

static __device__ __forceinline__ unsigned short f2bf(float f) {
    __hip_bfloat16 h = __float2bfloat16(f);
    return __builtin_bit_cast(unsigned short, h);
}
static __device__ __forceinline__ float bf2f(unsigned short u) {
    unsigned int x = ((unsigned int)u) << 16;
    return __builtin_bit_cast(float, x);
}

// ---------------- fused prep: count+rank | cvt x->bf16 | pack W1 | pack W2 ----------------
static __device__ __forceinline__ void pack_one(const float* __restrict__ W,
                                                unsigned short* __restrict__ Wp,
                                                int o, int NKS, int M) {
    int j    = o & 7;
    int lane = (o >> 3) & 63;
    int rest = o >> 9;
    int ks = rest % NKS;
    int ct = rest / NKS;
    int k = ks * 32 + (lane >> 4) * 8 + j;
    int m = ct * 16 + (lane & 15);
    Wp[o] = f2bf(W[(size_t)k * M + m]);
}

#define CVT_BLOCKS   512
#define PACK_BLOCKS  128     // 32768 / 256
#define COUNT_BLOCKS 1024
#define PREP_BLOCKS  (CVT_BLOCKS + 2 * PACK_BLOCKS + COUNT_BLOCKS)

__global__ __launch_bounds__(256) void prep_kernel(const float* __restrict__ x,
                                                   unsigned short* __restrict__ x16, int n4,
                                                   const float* __restrict__ W1,
                                                   unsigned short* __restrict__ w1p,
                                                   const float* __restrict__ W2,
                                                   unsigned short* __restrict__ w2p,
                                                   const int* __restrict__ dst,
                                                   int* __restrict__ cnt,
                                                   int* __restrict__ rank, int e, int n) {
    const int b = blockIdx.x, tid = threadIdx.x;
    if (b < CVT_BLOCKS) {
        for (int i = b * 256 + tid; i < n4; i += CVT_BLOCKS * 256) {
            float4 v = *(const float4*)&x[(size_t)i * 4];
            ushort4 o;
            o.x = f2bf(v.x); o.y = f2bf(v.y); o.z = f2bf(v.z); o.w = f2bf(v.w);
            *(ushort4*)&x16[(size_t)i * 4] = o;
        }
    } else if (b < CVT_BLOCKS + PACK_BLOCKS) {
        pack_one(W1, w1p, (b - CVT_BLOCKS) * 256 + tid, C_IN / 32, C_HID);
    } else if (b < CVT_BLOCKS + 2 * PACK_BLOCKS) {
        pack_one(W2, w2p, (b - CVT_BLOCKS - PACK_BLOCKS) * 256 + tid, C_HID / 32, C_OUT);
    } else {
        const int cb = b - CVT_BLOCKS - 2 * PACK_BLOCKS;
        for (int i = cb * 256 + tid; i < e; i += COUNT_BLOCKS * 256) {
            unsigned d = (unsigned)dst[i];
            int r = 0;
            if (d < (unsigned)n) r = atomicAdd(&cnt[d], 1);
            rank[i] = r;
        }
    }
}

// ---------------- multi-block scan (3 phases) ----------------
// phase 1: per-block sums (+ dinv)
__global__ __launch_bounds__(1024) void scan1_kernel(const int* __restrict__ cnt,
                                                     float* __restrict__ dinv,
                                                     int* __restrict__ bsum, int n) {
    const int tid = threadIdx.x, lane = tid & 63, w = tid >> 6;
    int i = blockIdx.x * 1024 + tid;
    int v = (i < n) ? cnt[i] : 0;
    if (i < n) dinv[i] = rsqrtf((float)(v + 1));    // +1 self loop
    int x = v;
    #pragma unroll
    for (int off = 32; off; off >>= 1) x += __shfl_xor(x, off);
    __shared__ int ws[16];
    if (lane == 0) ws[w] = x;
    __syncthreads();
    if (tid == 0) {
        int t = 0;
        #pragma unroll
        for (int j = 0; j < 16; ++j) t += ws[j];
        bsum[blockIdx.x] = t;
    }
}

// phase 2: single-block exclusive scan of bsum[nb] (nb <= 1024); writes row_start[n]=total
__global__ __launch_bounds__(1024) void scan2_kernel(int* __restrict__ bsum,
                                                     int* __restrict__ boff,
                                                     int* __restrict__ row_start,
                                                     int nb, int n) {
    const int tid = threadIdx.x, lane = tid & 63, w = tid >> 6;
    int v = (tid < nb) ? bsum[tid] : 0;
    int x = v;
    #pragma unroll
    for (int off = 1; off < 64; off <<= 1) {
        int y = __shfl_up(x, off);
        if (lane >= off) x += y;
    }
    __shared__ int ws[16];
    if (lane == 63) ws[w] = x;
    __syncthreads();
    int woff = 0, total = 0;
    #pragma unroll
    for (int j = 0; j < 16; ++j) {
        int s = ws[j];
        if (j < w) woff += s;
        total += s;
    }
    if (tid < nb) boff[tid] = woff + (x - v);
    if (tid == 0) row_start[n] = total;
}

// phase 3: per-block exclusive scan + block offset -> row_start
__global__ __launch_bounds__(1024) void scan3_kernel(const int* __restrict__ cnt,
                                                     const int* __restrict__ boff,
                                                     int* __restrict__ row_start, int n) {
    const int tid = threadIdx.x, lane = tid & 63, w = tid >> 6;
    int i = blockIdx.x * 1024 + tid;
    int v = (i < n) ? cnt[i] : 0;
    int x = v;
    #pragma unroll
    for (int off = 1; off < 64; off <<= 1) {
        int y = __shfl_up(x, off);
        if (lane >= off) x += y;
    }
    __shared__ int ws[16];
    if (lane == 63) ws[w] = x;
    __syncthreads();
    int woff = 0;
    #pragma unroll
    for (int j = 0; j < 16; ++j)
        if (j < w) woff += ws[j];
    if (i < n) row_start[i] = boff[blockIdx.x] + woff + (x - v);
}

// atomic-free scatter: p = row_start[d] + rank[i]
__global__ void fill_kernel(const int* __restrict__ src, const int* __restrict__ dst,
                            const int* __restrict__ rank, const int* __restrict__ row_start,
                            int* __restrict__ csr_src, int e, int n) {
    int i = blockIdx.x * blockDim.x + threadIdx.x;
    int stride = gridDim.x * blockDim.x;
    for (; i < e; i += stride) {
        unsigned d = (unsigned)dst[i];
        unsigned s = (unsigned)src[i];
        if (d < (unsigned)n && s < (unsigned)n) {
            int p = row_start[d] + rank[i];
            csr_src[p] = (int)s;
        }
    }
}

// ---------------- MFMA GEMM: C[n,M] bf16 = A[n,K] bf16 @ W[K,M] (packed bf16) ----------------
// Optional fused epilogue: relu(v + bias[col])
template<int K, int M, bool BIASRELU>
__global__ __launch_bounds__(256) void gemm_mfma_kernel(const unsigned short* __restrict__ A,
                                                        const unsigned short* __restrict__ Wp,
                                                        unsigned short* __restrict__ C,
                                                        const float* __restrict__ bias, int n) {
    constexpr int NKS = K / 32;
    constexpr int NCT = M / 16;
    __shared__ unsigned short wl[K * M];            // 64 KB
    const int tid  = threadIdx.x;
    const int lane = tid & 63;
    const int wid  = tid >> 6;

    for (int i = tid; i < K * M / 8; i += 256)
        *(uint4*)&wl[(size_t)i * 8] = *(const uint4*)&Wp[(size_t)i * 8];
    __syncthreads();

    const int ntiles = (n + 63) / 64;
    for (int t = blockIdx.x; t < ntiles; t += gridDim.x) {
        const int row0 = t * 64 + wid * 16;
        int arow = row0 + (lane & 15);
        if (arow > n - 1) arow = n - 1;             // clamp (garbage rows masked at store)
        const unsigned short* ap = A + (size_t)arow * K + (lane >> 4) * 8;

        short8 afrag[NKS];
        #pragma unroll
        for (int ks = 0; ks < NKS; ++ks)
            afrag[ks] = *(const short8*)(ap + ks * 32);

        f32x4 acc[NCT] = {};
        #pragma unroll
        for (int ks = 0; ks < NKS; ++ks) {
            #pragma unroll
            for (int ct = 0; ct < NCT; ++ct) {
                short8 b = *(const short8*)&wl[((ct * NKS + ks) * 64 + lane) * 8];
                acc[ct] = __builtin_amdgcn_mfma_f32_16x16x32_bf16(afrag[ks], b, acc[ct], 0, 0, 0);
            }
        }

        // C/D layout: col = lane&15, row = (lane>>4)*4 + r   [verified m89]
        const int crow0 = row0 + (lane >> 4) * 4;
        const int ccol  = lane & 15;
        #pragma unroll
        for (int ct = 0; ct < NCT; ++ct) {
            float bv = BIASRELU ? bias[ct * 16 + ccol] : 0.f;
            #pragma unroll
            for (int r = 0; r < 4; ++r) {
                int row = crow0 + r;
                if (row < n) {
                    float v = acc[ct][r];
                    if (BIASRELU) v = fmaxf(v + bv, 0.f);
                    C[(size_t)row * M + ct * 16 + ccol] = f2bf(v);
                }
            }
        }
    }
}

// ---------------- aggregation (bf16 H): out = [bias +] dinv[n]^2*H[n] + sum dinv[s]*dinv[n]*H[s]
// NPW nodes per wave (sub-wave of 64/NPW lanes each owns a node; 4 bf16 ch/lane).
// Edge loop unrolled x4 for memory-level parallelism.
template<int CH, int NPW, bool HASBIAS, bool RELU, bool LN>
__global__ __launch_bounds__(256) void agg_kernel(const unsigned short* __restrict__ H,
                                                  const int* __restrict__ row_start,
                                                  const int* __restrict__ csr_src,
                                                  const float* __restrict__ dinv,
                                                  const float* __restrict__ bias,
                                                  const float* __restrict__ gamma,
                                                  const float* __restrict__ beta,
                                                  void* __restrict__ out_v, int n) {
    constexpr int SUBW = 64 / NPW;                  // lanes per node
    static_assert(CH == SUBW * 4, "layout");
    const int lane = threadIdx.x & 63;
    const int wid  = threadIdx.x >> 6;
    int node = blockIdx.x * 4 * NPW + wid * NPW + (NPW == 2 ? (lane >> 5) : 0);
    if (NPW == 1) node = __builtin_amdgcn_readfirstlane(node);
    if (node >= n) return;
    const int slane = lane & (SUBW - 1);
    const int c0 = slane * 4;

    const float dn = dinv[node];
    const int e0 = row_start[node], e1 = row_start[node + 1];

    float acc[4];
    {   // self loop
        float c = dn * dn;
        ushort4 h = *(const ushort4*)&H[(size_t)node * CH + c0];
        acc[0] = bf2f(h.x) * c; acc[1] = bf2f(h.y) * c;
        acc[2] = bf2f(h.z) * c; acc[3] = bf2f(h.w) * c;
    }
    int e = e0;
    for (; e + 4 <= e1; e += 4) {
        int s0 = csr_src[e + 0], s1 = csr_src[e + 1];
        int s2 = csr_src[e + 2], s3 = csr_src[e + 3];
        float w0 = dinv[s0] * dn, w1 = dinv[s1] * dn;
        float w2 = dinv[s2] * dn, w3 = dinv[s3] * dn;
        ushort4 h0 = *(const ushort4*)&H[(size_t)s0 * CH + c0];
        ushort4 h1 = *(const ushort4*)&H[(size_t)s1 * CH + c0];
        ushort4 h2 = *(const ushort4*)&H[(size_t)s2 * CH + c0];
        ushort4 h3 = *(const ushort4*)&H[(size_t)s3 * CH + c0];
        acc[0] += bf2f(h0.x) * w0; acc[1] += bf2f(h0.y) * w0;
        acc[2] += bf2f(h0.z) * w0; acc[3] += bf2f(h0.w) * w0;
        acc[0] += bf2f(h1.x) * w1; acc[1] += bf2f(h1.y) * w1;
        acc[2] += bf2f(h1.z) * w1; acc[3] += bf2f(h1.w) * w1;
        acc[0] += bf2f(h2.x) * w2; acc[1] += bf2f(h2.y) * w2;
        acc[2] += bf2f(h2.z) * w2; acc[3] += bf2f(h2.w) * w2;
        acc[0] += bf2f(h3.x) * w3; acc[1] += bf2f(h3.y) * w3;
        acc[2] += bf2f(h3.z) * w3; acc[3] += bf2f(h3.w) * w3;
    }
    for (; e < e1; ++e) {
        int s = csr_src[e];
        float c = dinv[s] * dn;
        ushort4 h = *(const ushort4*)&H[(size_t)s * CH + c0];
        acc[0] += bf2f(h.x) * c; acc[1] += bf2f(h.y) * c;
        acc[2] += bf2f(h.z) * c; acc[3] += bf2f(h.w) * c;
    }

    if (HASBIAS) {
        float4 bi = *(const float4*)&bias[c0];
        acc[0] += bi.x; acc[1] += bi.y; acc[2] += bi.z; acc[3] += bi.w;
    }
    if (RELU) {
        #pragma unroll
        for (int v = 0; v < 4; ++v) acc[v] = fmaxf(acc[v], 0.f);
    }

    if (LN) {
        // fused LayerNorm over the sub-wave (SUBW lanes hold the full row)
        float s = acc[0] + acc[1] + acc[2] + acc[3];
        float ss = acc[0]*acc[0] + acc[1]*acc[1] + acc[2]*acc[2] + acc[3]*acc[3];
        #pragma unroll
        for (int off = SUBW / 2; off; off >>= 1) {
            s  += __shfl_xor(s, off);
            ss += __shfl_xor(ss, off);
        }
        float mu  = s * (1.f / (float)CH);
        float var = ss * (1.f / (float)CH) - mu * mu;
        float rstd = rsqrtf(var + 1e-5f);
        float4 g = *(const float4*)&gamma[c0];
        float4 b = *(const float4*)&beta[c0];
        f32x4 o;
        o[0] = (acc[0] - mu) * rstd * g.x + b.x;
        o[1] = (acc[1] - mu) * rstd * g.y + b.y;
        o[2] = (acc[2] - mu) * rstd * g.z + b.z;
        o[3] = (acc[3] - mu) * rstd * g.w + b.w;
        float* out = (float*)out_v;
        __builtin_nontemporal_store(o, (f32x4*)&out[(size_t)node * CH + c0]);  // final out: write-only
    } else {
        ushort4 o4;
        o4.x = f2bf(acc[0]); o4.y = f2bf(acc[1]);
        o4.z = f2bf(acc[2]); o4.w = f2bf(acc[3]);
        unsigned short* out = (unsigned short*)out_v;
        *(ushort4*)&out[(size_t)node * CH + c0] = o4;   // plain store: re-read by next gemm
    }
}

extern "C" void kernel_launch(void* const* d_in, const int* in_sizes, int n_in,
                              void* d_out, int out_size, void* d_ws, size_t ws_size,
                              hipStream_t stream) {
    const float* x     = (const float*)d_in[0];
    const int*   ei    = (const int*)d_in[1];     // int32 (harness: integer -> const int*)
    const float* W1    = (const float*)d_in[2];
    const float* b1    = (const float*)d_in[3];
    const float* W2    = (const float*)d_in[4];
    const float* b2    = (const float*)d_in[5];
    const float* gamma = (const float*)d_in[6];
    const float* beta  = (const float*)d_in[7];
    float* out = (float*)d_out;

    const int N = in_sizes[0] / C_IN;
    const int E = in_sizes[1] / 2;
    const int* src = ei;
    const int* dst = ei + E;
    const int NB = (N + 1023) / 1024;

    // workspace layout
    unsigned short* x16 = (unsigned short*)d_ws;            // N*128 (x in bf16)
    unsigned short* xa  = x16 + (size_t)N * C_IN;           // N*128 (S·x)
    unsigned short* g16 = xa + (size_t)N * C_IN;            // N*256 (relu(S·x@W1+b1))
    unsigned short* h2  = g16 + (size_t)N * C_HID;          // N*128 (g@W2)
    unsigned short* w1p = h2 + (size_t)N * C_OUT;           // 128*256
    unsigned short* w2p = w1p + C_IN * C_HID;               // 256*128
    float* dinv  = (float*)(w2p + C_HID * C_OUT);           // N
    int*   cnt   = (int*)(dinv + N);                        // N
    int*   row_start = cnt + N;                             // N+1 (pad 4)
    int*   bsum      = row_start + N + 4;                   // NB
    int*   boff      = bsum + NB;                           // NB (pad to 4)
    int*   rank      = boff + NB + 4;                       // E
    int*   csr_src   = rank + E;                            // E

    hipMemsetAsync(cnt, 0, (size_t)N * sizeof(int), stream);

    // fused: count+rank | cvt x | pack W1 | pack W2
    prep_kernel<<<PREP_BLOCKS, 256, 0, stream>>>(x, x16, N * C_IN / 4,
                                                 W1, w1p, W2, w2p,
                                                 dst, cnt, rank, E, N);
    // multi-block scan
    scan1_kernel<<<NB, 1024, 0, stream>>>(cnt, dinv, bsum, N);
    scan2_kernel<<<1, 1024, 0, stream>>>(bsum, boff, row_start, NB, N);
    scan3_kernel<<<NB, 1024, 0, stream>>>(cnt, boff, row_start, N);

    fill_kernel<<<2048, 256, 0, stream>>>(src, dst, rank, row_start, csr_src, E, N);

    // layer 1 (reordered by linearity): xa = S·x ; g = relu(xa@W1 + b1)
    agg_kernel<C_IN, 2, false, false, false><<<(N + 7) / 8, 256, 0, stream>>>(
        x16, row_start, csr_src, dinv, nullptr, nullptr, nullptr, (void*)xa, N);
    gemm_mfma_kernel<C_IN, C_HID, true><<<512, 256, 0, stream>>>(xa, w1p, g16, b1, N);

    // layer 2: h2 = g@W2 ; out = LN(S·h2 + b2)
    gemm_mfma_kernel<C_HID, C_OUT, false><<<512, 256, 0, stream>>>(g16, w2p, h2, nullptr, N);
    agg_kernel<C_OUT, 2, true, false, true><<<(N + 7) / 8, 256, 0, stream>>>(
        h2, row_start, csr_src, dinv, b2, gamma, beta, (void*)out, N);
}

// Round 16
// 264.797 us; speedup vs baseline: 5.2894x; 1.1698x over previous
//
#include <hip/hip_runtime.h>
#include <hip/hip_bf16.h>

// ---------------- constants ----------------
#define C_IN  128
#define C_HID 256
#define C_OUT 128

#define BIN_SHIFT 10
#define BIN_SIZE  1024
#define NBINS_MAX 128
#define CAP       32768          // per-bin capacity (mean ~16.3K for uniform random)
#define CHUNK_A   8192           // edges per bin-append block

typedef __attribute__((ext_vector_type(8))) short short8;
typedef __attribute__((ext_vector_type(4))) float f32x4;

static __device__ __forceinline__ unsigned short f2bf(float f) {
    __hip_bfloat16 h = __float2bfloat16(f);
    return __builtin_bit_cast(unsigned short, h);
}
static __device__ __forceinline__ float bf2f(unsigned short u) {
    unsigned int x = ((unsigned int)u) << 16;
    return __builtin_bit_cast(float, x);
}

// ---------------- fused prep: cvt x->bf16 | pack W1 | pack W2 | bin-append edges ----------------
static __device__ __forceinline__ void pack_one(const float* __restrict__ W,
                                                unsigned short* __restrict__ Wp,
                                                int o, int NKS, int M) {
    int j    = o & 7;
    int lane = (o >> 3) & 63;
    int rest = o >> 9;
    int ks = rest % NKS;
    int ct = rest / NKS;
    int k = ks * 32 + (lane >> 4) * 8 + j;
    int m = ct * 16 + (lane & 15);
    Wp[o] = f2bf(W[(size_t)k * M + m]);
}

#define CVT_BLOCKS   512
#define PACK_BLOCKS  128     // 32768 / 256

__global__ __launch_bounds__(256) void prep_kernel(const float* __restrict__ x,
                                                   unsigned short* __restrict__ x16, int n4,
                                                   const float* __restrict__ W1,
                                                   unsigned short* __restrict__ w1p,
                                                   const float* __restrict__ W2,
                                                   unsigned short* __restrict__ w2p,
                                                   const int* __restrict__ src,
                                                   const int* __restrict__ dst,
                                                   unsigned int* __restrict__ binned,
                                                   int* __restrict__ gbin_cnt,
                                                   int e, int n) {
    __shared__ int lh[NBINS_MAX];    // sweep-1 local histogram
    __shared__ int lgb[NBINS_MAX];   // global base per bin for this block
    __shared__ int lh2[NBINS_MAX];   // sweep-2 rank counters
    const int b = blockIdx.x, tid = threadIdx.x;
    if (b < CVT_BLOCKS) {
        for (int i = b * 256 + tid; i < n4; i += CVT_BLOCKS * 256) {
            float4 v = *(const float4*)&x[(size_t)i * 4];
            ushort4 o;
            o.x = f2bf(v.x); o.y = f2bf(v.y); o.z = f2bf(v.z); o.w = f2bf(v.w);
            *(ushort4*)&x16[(size_t)i * 4] = o;
        }
    } else if (b < CVT_BLOCKS + PACK_BLOCKS) {
        pack_one(W1, w1p, (b - CVT_BLOCKS) * 256 + tid, C_IN / 32, C_HID);
    } else if (b < CVT_BLOCKS + 2 * PACK_BLOCKS) {
        pack_one(W2, w2p, (b - CVT_BLOCKS - PACK_BLOCKS) * 256 + tid, C_HID / 32, C_OUT);
    } else {
        const int cb = b - CVT_BLOCKS - 2 * PACK_BLOCKS;
        const int start = cb * CHUNK_A;
        const int end = min(start + CHUNK_A, e);
        const int nbins = (n + BIN_SIZE - 1) >> BIN_SHIFT;
        for (int j = tid; j < nbins; j += 256) { lh[j] = 0; lh2[j] = 0; }
        __syncthreads();
        for (int i = start + tid; i < end; i += 256) {
            unsigned d = (unsigned)dst[i], s = (unsigned)src[i];
            if (d < (unsigned)n && s < (unsigned)n)
                atomicAdd(&lh[d >> BIN_SHIFT], 1);
        }
        __syncthreads();
        for (int j = tid; j < nbins; j += 256) {
            int c = lh[j];
            lgb[j] = c ? atomicAdd(&gbin_cnt[j], c) : 0;
        }
        __syncthreads();
        for (int i = start + tid; i < end; i += 256) {
            unsigned d = (unsigned)dst[i], s = (unsigned)src[i];
            if (d < (unsigned)n && s < (unsigned)n) {
                int bin = d >> BIN_SHIFT;
                int r = atomicAdd(&lh2[bin], 1);
                int pos = lgb[bin] + r;
                if (pos < CAP)
                    binned[(size_t)bin * CAP + pos] = (s << BIN_SHIFT) | (d & (BIN_SIZE - 1));
            }
        }
    }
}

// ---------------- bin scan: exclusive scan of gbin_cnt[nbins] -> bin_base; row_start[n]=total
__global__ __launch_bounds__(1024) void binscan_kernel(const int* __restrict__ gbin_cnt,
                                                       int* __restrict__ bin_base,
                                                       int* __restrict__ row_start,
                                                       int nbins, int n) {
    const int tid = threadIdx.x, lane = tid & 63, w = tid >> 6;
    int v = (tid < nbins) ? gbin_cnt[tid] : 0;
    int x = v;
    #pragma unroll
    for (int off = 1; off < 64; off <<= 1) {
        int y = __shfl_up(x, off);
        if (lane >= off) x += y;
    }
    __shared__ int ws[16];
    if (lane == 63) ws[w] = x;
    __syncthreads();
    int woff = 0, total = 0;
    #pragma unroll
    for (int j = 0; j < 16; ++j) {
        int s = ws[j];
        if (j < w) woff += s;
        total += s;
    }
    if (tid < nbins) bin_base[tid] = woff + (x - v);
    if (tid == 0) { bin_base[nbins] = total; row_start[n] = total; }
}

// ---------------- per-bin CSR build: block b owns nodes [b*1024, b*1024+1024)
__global__ __launch_bounds__(1024) void bincsr_kernel(const unsigned int* __restrict__ binned,
                                                      const int* __restrict__ bin_base,
                                                      int* __restrict__ csr_src,
                                                      int* __restrict__ row_start,
                                                      float* __restrict__ dinv, int n) {
    __shared__ int h[BIN_SIZE];
    __shared__ int ex[BIN_SIZE];
    __shared__ int ws[16];
    const int b = blockIdx.x, tid = threadIdx.x, lane = tid & 63, w = tid >> 6;
    h[tid] = 0;
    __syncthreads();
    const int base  = bin_base[b];
    int cnt_b = bin_base[b + 1] - base;
    if (cnt_b > CAP) cnt_b = CAP;                    // safety clamp
    const size_t boff = (size_t)b * CAP;
    for (int i = tid; i < cnt_b; i += BIN_SIZE)
        atomicAdd(&h[binned[boff + i] & (BIN_SIZE - 1)], 1);
    __syncthreads();
    const int v = h[tid];
    int x = v;
    #pragma unroll
    for (int off = 1; off < 64; off <<= 1) {
        int y = __shfl_up(x, off);
        if (lane >= off) x += y;
    }
    if (lane == 63) ws[w] = x;
    __syncthreads();
    int woff = 0;
    #pragma unroll
    for (int j = 0; j < 16; ++j)
        if (j < w) woff += ws[j];
    const int excl = woff + (x - v);
    ex[tid] = excl;
    const int node = b * BIN_SIZE + tid;
    if (node < n) {
        row_start[node] = base + excl;
        dinv[node] = rsqrtf((float)(v + 1));         // +1 self loop
    }
    __syncthreads();
    h[tid] = 0;                                      // reuse as rank counters
    __syncthreads();
    for (int i = tid; i < cnt_b; i += BIN_SIZE) {
        unsigned p = binned[boff + i];
        int dl = p & (BIN_SIZE - 1);
        int r = atomicAdd(&h[dl], 1);
        csr_src[base + ex[dl] + r] = (int)(p >> BIN_SHIFT);
    }
}

// ---------------- MFMA GEMM: C[n,M] bf16 = A[n,K] bf16 @ W[K,M] (packed bf16) ----------------
// Optional fused epilogue: relu(v + bias[col])
template<int K, int M, bool BIASRELU>
__global__ __launch_bounds__(256) void gemm_mfma_kernel(const unsigned short* __restrict__ A,
                                                        const unsigned short* __restrict__ Wp,
                                                        unsigned short* __restrict__ C,
                                                        const float* __restrict__ bias, int n) {
    constexpr int NKS = K / 32;
    constexpr int NCT = M / 16;
    __shared__ unsigned short wl[K * M];            // 64 KB
    const int tid  = threadIdx.x;
    const int lane = tid & 63;
    const int wid  = tid >> 6;

    for (int i = tid; i < K * M / 8; i += 256)
        *(uint4*)&wl[(size_t)i * 8] = *(const uint4*)&Wp[(size_t)i * 8];
    __syncthreads();

    const int ntiles = (n + 63) / 64;
    for (int t = blockIdx.x; t < ntiles; t += gridDim.x) {
        const int row0 = t * 64 + wid * 16;
        int arow = row0 + (lane & 15);
        if (arow > n - 1) arow = n - 1;             // clamp (garbage rows masked at store)
        const unsigned short* ap = A + (size_t)arow * K + (lane >> 4) * 8;

        short8 afrag[NKS];
        #pragma unroll
        for (int ks = 0; ks < NKS; ++ks)
            afrag[ks] = *(const short8*)(ap + ks * 32);

        f32x4 acc[NCT] = {};
        #pragma unroll
        for (int ks = 0; ks < NKS; ++ks) {
            #pragma unroll
            for (int ct = 0; ct < NCT; ++ct) {
                short8 b = *(const short8*)&wl[((ct * NKS + ks) * 64 + lane) * 8];
                acc[ct] = __builtin_amdgcn_mfma_f32_16x16x32_bf16(afrag[ks], b, acc[ct], 0, 0, 0);
            }
        }

        // C/D layout: col = lane&15, row = (lane>>4)*4 + r   [verified m89]
        const int crow0 = row0 + (lane >> 4) * 4;
        const int ccol  = lane & 15;
        #pragma unroll
        for (int ct = 0; ct < NCT; ++ct) {
            float bv = BIASRELU ? bias[ct * 16 + ccol] : 0.f;
            #pragma unroll
            for (int r = 0; r < 4; ++r) {
                int row = crow0 + r;
                if (row < n) {
                    float v = acc[ct][r];
                    if (BIASRELU) v = fmaxf(v + bv, 0.f);
                    C[(size_t)row * M + ct * 16 + ccol] = f2bf(v);
                }
            }
        }
    }
}

// ---------------- aggregation (bf16 H): out = [bias +] dinv[n]^2*H[n] + sum dinv[s]*dinv[n]*H[s]
// NPW nodes per wave (sub-wave of 64/NPW lanes each owns a node; 4 bf16 ch/lane).
// Edge loop unrolled x4 for memory-level parallelism.
template<int CH, int NPW, bool HASBIAS, bool RELU, bool LN>
__global__ __launch_bounds__(256) void agg_kernel(const unsigned short* __restrict__ H,
                                                  const int* __restrict__ row_start,
                                                  const int* __restrict__ csr_src,
                                                  const float* __restrict__ dinv,
                                                  const float* __restrict__ bias,
                                                  const float* __restrict__ gamma,
                                                  const float* __restrict__ beta,
                                                  void* __restrict__ out_v, int n) {
    constexpr int SUBW = 64 / NPW;                  // lanes per node
    static_assert(CH == SUBW * 4, "layout");
    const int lane = threadIdx.x & 63;
    const int wid  = threadIdx.x >> 6;
    int node = blockIdx.x * 4 * NPW + wid * NPW + (NPW == 2 ? (lane >> 5) : 0);
    if (NPW == 1) node = __builtin_amdgcn_readfirstlane(node);
    if (node >= n) return;
    const int slane = lane & (SUBW - 1);
    const int c0 = slane * 4;

    const float dn = dinv[node];
    const int e0 = row_start[node], e1 = row_start[node + 1];

    float acc[4];
    {   // self loop
        float c = dn * dn;
        ushort4 h = *(const ushort4*)&H[(size_t)node * CH + c0];
        acc[0] = bf2f(h.x) * c; acc[1] = bf2f(h.y) * c;
        acc[2] = bf2f(h.z) * c; acc[3] = bf2f(h.w) * c;
    }
    int e = e0;
    for (; e + 4 <= e1; e += 4) {
        int s0 = csr_src[e + 0], s1 = csr_src[e + 1];
        int s2 = csr_src[e + 2], s3 = csr_src[e + 3];
        float w0 = dinv[s0] * dn, w1 = dinv[s1] * dn;
        float w2 = dinv[s2] * dn, w3 = dinv[s3] * dn;
        ushort4 h0 = *(const ushort4*)&H[(size_t)s0 * CH + c0];
        ushort4 h1 = *(const ushort4*)&H[(size_t)s1 * CH + c0];
        ushort4 h2 = *(const ushort4*)&H[(size_t)s2 * CH + c0];
        ushort4 h3 = *(const ushort4*)&H[(size_t)s3 * CH + c0];
        acc[0] += bf2f(h0.x) * w0; acc[1] += bf2f(h0.y) * w0;
        acc[2] += bf2f(h0.z) * w0; acc[3] += bf2f(h0.w) * w0;
        acc[0] += bf2f(h1.x) * w1; acc[1] += bf2f(h1.y) * w1;
        acc[2] += bf2f(h1.z) * w1; acc[3] += bf2f(h1.w) * w1;
        acc[0] += bf2f(h2.x) * w2; acc[1] += bf2f(h2.y) * w2;
        acc[2] += bf2f(h2.z) * w2; acc[3] += bf2f(h2.w) * w2;
        acc[0] += bf2f(h3.x) * w3; acc[1] += bf2f(h3.y) * w3;
        acc[2] += bf2f(h3.z) * w3; acc[3] += bf2f(h3.w) * w3;
    }
    for (; e < e1; ++e) {
        int s = csr_src[e];
        float c = dinv[s] * dn;
        ushort4 h = *(const ushort4*)&H[(size_t)s * CH + c0];
        acc[0] += bf2f(h.x) * c; acc[1] += bf2f(h.y) * c;
        acc[2] += bf2f(h.z) * c; acc[3] += bf2f(h.w) * c;
    }

    if (HASBIAS) {
        float4 bi = *(const float4*)&bias[c0];
        acc[0] += bi.x; acc[1] += bi.y; acc[2] += bi.z; acc[3] += bi.w;
    }
    if (RELU) {
        #pragma unroll
        for (int v = 0; v < 4; ++v) acc[v] = fmaxf(acc[v], 0.f);
    }

    if (LN) {
        // fused LayerNorm over the sub-wave (SUBW lanes hold the full row)
        float s = acc[0] + acc[1] + acc[2] + acc[3];
        float ss = acc[0]*acc[0] + acc[1]*acc[1] + acc[2]*acc[2] + acc[3]*acc[3];
        #pragma unroll
        for (int off = SUBW / 2; off; off >>= 1) {
            s  += __shfl_xor(s, off);
            ss += __shfl_xor(ss, off);
        }
        float mu  = s * (1.f / (float)CH);
        float var = ss * (1.f / (float)CH) - mu * mu;
        float rstd = rsqrtf(var + 1e-5f);
        float4 g = *(const float4*)&gamma[c0];
        float4 b = *(const float4*)&beta[c0];
        f32x4 o;
        o[0] = (acc[0] - mu) * rstd * g.x + b.x;
        o[1] = (acc[1] - mu) * rstd * g.y + b.y;
        o[2] = (acc[2] - mu) * rstd * g.z + b.z;
        o[3] = (acc[3] - mu) * rstd * g.w + b.w;
        float* out = (float*)out_v;
        __builtin_nontemporal_store(o, (f32x4*)&out[(size_t)node * CH + c0]);  // final out: write-only
    } else {
        ushort4 o4;
        o4.x = f2bf(acc[0]); o4.y = f2bf(acc[1]);
        o4.z = f2bf(acc[2]); o4.w = f2bf(acc[3]);
        unsigned short* out = (unsigned short*)out_v;
        *(ushort4*)&out[(size_t)node * CH + c0] = o4;   // plain store: re-read by next gemm
    }
}

extern "C" void kernel_launch(void* const* d_in, const int* in_sizes, int n_in,
                              void* d_out, int out_size, void* d_ws, size_t ws_size,
                              hipStream_t stream) {
    const float* x     = (const float*)d_in[0];
    const int*   ei    = (const int*)d_in[1];     // int32 (harness: integer -> const int*)
    const float* W1    = (const float*)d_in[2];
    const float* b1    = (const float*)d_in[3];
    const float* W2    = (const float*)d_in[4];
    const float* b2    = (const float*)d_in[5];
    const float* gamma = (const float*)d_in[6];
    const float* beta  = (const float*)d_in[7];
    float* out = (float*)d_out;

    const int N = in_sizes[0] / C_IN;
    const int E = in_sizes[1] / 2;
    const int* src = ei;
    const int* dst = ei + E;
    const int NBINS = (N + BIN_SIZE - 1) >> BIN_SHIFT;
    const int NBINA = (E + CHUNK_A - 1) / CHUNK_A;

    // workspace layout
    unsigned short* x16 = (unsigned short*)d_ws;            // N*128 (x in bf16)
    unsigned short* xa  = x16 + (size_t)N * C_IN;           // N*128 (S·x)
    unsigned short* g16 = xa + (size_t)N * C_IN;            // N*256 (relu(S·x@W1+b1))
    unsigned short* h2  = g16 + (size_t)N * C_HID;          // N*128 (g@W2)
    unsigned short* w1p = h2 + (size_t)N * C_OUT;           // 128*256
    unsigned short* w2p = w1p + C_IN * C_HID;               // 256*128
    float* dinv  = (float*)(w2p + C_HID * C_OUT);           // N
    int*   row_start = (int*)(dinv + N);                    // N+1 (pad 4)
    int*   gbin_cnt  = row_start + N + 4;                   // NBINS_MAX
    int*   bin_base  = gbin_cnt + NBINS_MAX;                // NBINS_MAX+4
    unsigned int* binned = (unsigned int*)(bin_base + NBINS_MAX + 4);  // NBINS_MAX*CAP
    int*   csr_src   = (int*)(binned + (size_t)NBINS_MAX * CAP);       // E

    hipMemsetAsync(gbin_cnt, 0, NBINS_MAX * sizeof(int), stream);

    // fused: cvt x | pack W1 | pack W2 | bin-append edges
    prep_kernel<<<CVT_BLOCKS + 2 * PACK_BLOCKS + NBINA, 256, 0, stream>>>(
        x, x16, N * C_IN / 4, W1, w1p, W2, w2p, src, dst, binned, gbin_cnt, E, N);
    binscan_kernel<<<1, 1024, 0, stream>>>(gbin_cnt, bin_base, row_start, NBINS, N);
    bincsr_kernel<<<NBINS, 1024, 0, stream>>>(binned, bin_base, csr_src, row_start, dinv, N);

    // layer 1 (reordered by linearity): xa = S·x ; g = relu(xa@W1 + b1)
    agg_kernel<C_IN, 2, false, false, false><<<(N + 7) / 8, 256, 0, stream>>>(
        x16, row_start, csr_src, dinv, nullptr, nullptr, nullptr, (void*)xa, N);
    gemm_mfma_kernel<C_IN, C_HID, true><<<512, 256, 0, stream>>>(xa, w1p, g16, b1, N);

    // layer 2: h2 = g@W2 ; out = LN(S·h2 + b2)
    gemm_mfma_kernel<C_HID, C_OUT, false><<<512, 256, 0, stream>>>(g16, w2p, h2, nullptr, N);
    agg_kernel<C_OUT, 2, true, false, true><<<(N + 7) / 8, 256, 0, stream>>>(
        h2, row_start, csr_src, dinv, b2, gamma, beta, (void*)out, N);
}

// Round 19
// 245.527 us; speedup vs baseline: 5.7046x; 1.0785x over previous
//
#include <hip/hip_runtime.h>
#include <hip/hip_bf16.h>

// ---------------- constants ----------------
#define C_IN  128
#define C_HID 256
#define C_OUT 128

#define BIN_SHIFT 10
#define BIN_SIZE  1024
#define NBINS_MAX 128
#define CAP       32768          // per-bin capacity (mean ~16.3K for uniform random)
#define CHUNK_A   8192           // edges per bin-append block

typedef __attribute__((ext_vector_type(8))) short short8;
typedef __attribute__((ext_vector_type(4))) float f32x4;

static __device__ __forceinline__ unsigned short f2bf(float f) {
    __hip_bfloat16 h = __float2bfloat16(f);
    return __builtin_bit_cast(unsigned short, h);
}
static __device__ __forceinline__ float bf2f(unsigned short u) {
    unsigned int x = ((unsigned int)u) << 16;
    return __builtin_bit_cast(float, x);
}

// ---------------- fused prep: quant x->int8/row-scale | pack W1 | pack W2 | bin-append ----------------
static __device__ __forceinline__ void pack_one(const float* __restrict__ W,
                                                unsigned short* __restrict__ Wp,
                                                int o, int NKS, int M) {
    int j    = o & 7;
    int lane = (o >> 3) & 63;
    int rest = o >> 9;
    int ks = rest % NKS;
    int ct = rest / NKS;
    int k = ks * 32 + (lane >> 4) * 8 + j;
    int m = ct * 16 + (lane & 15);
    Wp[o] = f2bf(W[(size_t)k * M + m]);
}

#define CVT_BLOCKS   512
#define PACK_BLOCKS  128     // 32768 / 256

__global__ __launch_bounds__(256) void prep_kernel(const float* __restrict__ x,
                                                   unsigned char* __restrict__ xq,
                                                   float* __restrict__ xscale,
                                                   const float* __restrict__ W1,
                                                   unsigned short* __restrict__ w1p,
                                                   const float* __restrict__ W2,
                                                   unsigned short* __restrict__ w2p,
                                                   const int* __restrict__ src,
                                                   const int* __restrict__ dst,
                                                   unsigned int* __restrict__ binned,
                                                   int* __restrict__ gbin_cnt,
                                                   int e, int n) {
    __shared__ int lh[NBINS_MAX];    // sweep-1 local histogram
    __shared__ int lgb[NBINS_MAX];   // global base per bin for this block
    __shared__ int lh2[NBINS_MAX];   // sweep-2 rank counters
    const int b = blockIdx.x, tid = threadIdx.x;
    if (b < CVT_BLOCKS) {
        // int8 row quantization: 32 lanes per row, 8 rows per block, grid-stride
        const int slane = tid & 31;
        const int subrow = tid >> 5;
        for (int row = b * 8 + subrow; row < n; row += CVT_BLOCKS * 8) {
            float4 v = *(const float4*)&x[(size_t)row * C_IN + slane * 4];
            float m = fmaxf(fmaxf(fabsf(v.x), fabsf(v.y)), fmaxf(fabsf(v.z), fabsf(v.w)));
            #pragma unroll
            for (int off = 16; off; off >>= 1) m = fmaxf(m, __shfl_xor(m, off));
            float inv = (m > 0.f) ? 127.f / m : 0.f;
            int q0 = (int)rintf(v.x * inv), q1 = (int)rintf(v.y * inv);
            int q2 = (int)rintf(v.z * inv), q3 = (int)rintf(v.w * inv);
            unsigned int p = ((unsigned)q0 & 0xff) | (((unsigned)q1 & 0xff) << 8) |
                             (((unsigned)q2 & 0xff) << 16) | (((unsigned)q3 & 0xff) << 24);
            *(unsigned int*)&xq[(size_t)row * C_IN + slane * 4] = p;
            if (slane == 0) xscale[row] = m * (1.f / 127.f);
        }
    } else if (b < CVT_BLOCKS + PACK_BLOCKS) {
        pack_one(W1, w1p, (b - CVT_BLOCKS) * 256 + tid, C_IN / 32, C_HID);
    } else if (b < CVT_BLOCKS + 2 * PACK_BLOCKS) {
        pack_one(W2, w2p, (b - CVT_BLOCKS - PACK_BLOCKS) * 256 + tid, C_HID / 32, C_OUT);
    } else {
        const int cb = b - CVT_BLOCKS - 2 * PACK_BLOCKS;
        const int start = cb * CHUNK_A;
        const int end = min(start + CHUNK_A, e);
        const int nbins = (n + BIN_SIZE - 1) >> BIN_SHIFT;
        for (int j = tid; j < nbins; j += 256) { lh[j] = 0; lh2[j] = 0; }
        __syncthreads();
        for (int i = start + tid; i < end; i += 256) {
            unsigned d = (unsigned)dst[i], s = (unsigned)src[i];
            if (d < (unsigned)n && s < (unsigned)n)
                atomicAdd(&lh[d >> BIN_SHIFT], 1);
        }
        __syncthreads();
        for (int j = tid; j < nbins; j += 256) {
            int c = lh[j];
            lgb[j] = c ? atomicAdd(&gbin_cnt[j], c) : 0;
        }
        __syncthreads();
        for (int i = start + tid; i < end; i += 256) {
            unsigned d = (unsigned)dst[i], s = (unsigned)src[i];
            if (d < (unsigned)n && s < (unsigned)n) {
                int bin = d >> BIN_SHIFT;
                int r = atomicAdd(&lh2[bin], 1);
                int pos = lgb[bin] + r;
                if (pos < CAP)
                    binned[(size_t)bin * CAP + pos] = (s << BIN_SHIFT) | (d & (BIN_SIZE - 1));
            }
        }
    }
}

// ---------------- bin scan: exclusive scan of gbin_cnt[nbins] -> bin_base; row_start[n]=total
__global__ __launch_bounds__(1024) void binscan_kernel(const int* __restrict__ gbin_cnt,
                                                       int* __restrict__ bin_base,
                                                       int* __restrict__ row_start,
                                                       int nbins, int n) {
    const int tid = threadIdx.x, lane = tid & 63, w = tid >> 6;
    int v = (tid < nbins) ? gbin_cnt[tid] : 0;
    int x = v;
    #pragma unroll
    for (int off = 1; off < 64; off <<= 1) {
        int y = __shfl_up(x, off);
        if (lane >= off) x += y;
    }
    __shared__ int ws[16];
    if (lane == 63) ws[w] = x;
    __syncthreads();
    int woff = 0, total = 0;
    #pragma unroll
    for (int j = 0; j < 16; ++j) {
        int s = ws[j];
        if (j < w) woff += s;
        total += s;
    }
    if (tid < nbins) bin_base[tid] = woff + (x - v);
    if (tid == 0) { bin_base[nbins] = total; row_start[n] = total; }
}

// ---------------- per-bin CSR build: block b owns nodes [b*1024, b*1024+1024)
// also writes dinv and dscale = dinv*xscale
__global__ __launch_bounds__(1024) void bincsr_kernel(const unsigned int* __restrict__ binned,
                                                      const int* __restrict__ bin_base,
                                                      const float* __restrict__ xscale,
                                                      int* __restrict__ csr_src,
                                                      int* __restrict__ row_start,
                                                      float* __restrict__ dinv,
                                                      float* __restrict__ dscale, int n) {
    __shared__ int h[BIN_SIZE];
    __shared__ int ex[BIN_SIZE];
    __shared__ int ws[16];
    const int b = blockIdx.x, tid = threadIdx.x, lane = tid & 63, w = tid >> 6;
    h[tid] = 0;
    __syncthreads();
    const int base  = bin_base[b];
    int cnt_b = bin_base[b + 1] - base;
    if (cnt_b > CAP) cnt_b = CAP;                    // safety clamp
    const size_t boff = (size_t)b * CAP;
    for (int i = tid; i < cnt_b; i += BIN_SIZE)
        atomicAdd(&h[binned[boff + i] & (BIN_SIZE - 1)], 1);
    __syncthreads();
    const int v = h[tid];
    int x = v;
    #pragma unroll
    for (int off = 1; off < 64; off <<= 1) {
        int y = __shfl_up(x, off);
        if (lane >= off) x += y;
    }
    if (lane == 63) ws[w] = x;
    __syncthreads();
    int woff = 0;
    #pragma unroll
    for (int j = 0; j < 16; ++j)
        if (j < w) woff += ws[j];
    const int excl = woff + (x - v);
    ex[tid] = excl;
    const int node = b * BIN_SIZE + tid;
    if (node < n) {
        row_start[node] = base + excl;
        float di = rsqrtf((float)(v + 1));           // +1 self loop
        dinv[node] = di;
        dscale[node] = di * xscale[node];
    }
    __syncthreads();
    h[tid] = 0;                                      // reuse as rank counters
    __syncthreads();
    for (int i = tid; i < cnt_b; i += BIN_SIZE) {
        unsigned p = binned[boff + i];
        int dl = p & (BIN_SIZE - 1);
        int r = atomicAdd(&h[dl], 1);
        csr_src[base + ex[dl] + r] = (int)(p >> BIN_SHIFT);
    }
}

// ---------------- MFMA GEMM: C[n,M] bf16 = A[n,K] bf16 @ W[K,M] (packed bf16) ----------------
// Optional fused epilogue: relu(v + bias[col])
template<int K, int M, bool BIASRELU>
__global__ __launch_bounds__(256) void gemm_mfma_kernel(const unsigned short* __restrict__ A,
                                                        const unsigned short* __restrict__ Wp,
                                                        unsigned short* __restrict__ C,
                                                        const float* __restrict__ bias, int n) {
    constexpr int NKS = K / 32;
    constexpr int NCT = M / 16;
    __shared__ unsigned short wl[K * M];            // 64 KB
    const int tid  = threadIdx.x;
    const int lane = tid & 63;
    const int wid  = tid >> 6;

    for (int i = tid; i < K * M / 8; i += 256)
        *(uint4*)&wl[(size_t)i * 8] = *(const uint4*)&Wp[(size_t)i * 8];
    __syncthreads();

    const int ntiles = (n + 63) / 64;
    for (int t = blockIdx.x; t < ntiles; t += gridDim.x) {
        const int row0 = t * 64 + wid * 16;
        int arow = row0 + (lane & 15);
        if (arow > n - 1) arow = n - 1;             // clamp (garbage rows masked at store)
        const unsigned short* ap = A + (size_t)arow * K + (lane >> 4) * 8;

        short8 afrag[NKS];
        #pragma unroll
        for (int ks = 0; ks < NKS; ++ks)
            afrag[ks] = *(const short8*)(ap + ks * 32);

        f32x4 acc[NCT] = {};
        #pragma unroll
        for (int ks = 0; ks < NKS; ++ks) {
            #pragma unroll
            for (int ct = 0; ct < NCT; ++ct) {
                short8 b = *(const short8*)&wl[((ct * NKS + ks) * 64 + lane) * 8];
                acc[ct] = __builtin_amdgcn_mfma_f32_16x16x32_bf16(afrag[ks], b, acc[ct], 0, 0, 0);
            }
        }

        // C/D layout: col = lane&15, row = (lane>>4)*4 + r   [verified m89]
        const int crow0 = row0 + (lane >> 4) * 4;
        const int ccol  = lane & 15;
        #pragma unroll
        for (int ct = 0; ct < NCT; ++ct) {
            float bv = BIASRELU ? bias[ct * 16 + ccol] : 0.f;
            #pragma unroll
            for (int r = 0; r < 4; ++r) {
                int row = crow0 + r;
                if (row < n) {
                    float v = acc[ct][r];
                    if (BIASRELU) v = fmaxf(v + bv, 0.f);
                    C[(size_t)row * M + ct * 16 + ccol] = f2bf(v);
                }
            }
        }
    }
}

// ---------------- aggregation: out = [bias +] cw[n]*dn*H[n] + sum cw[s]*dn*H[s]
// cw = dinv (bf16 H) or dscale=dinv*xscale (int8 H). dn = dinv[node].
// CH=128: 2 nodes/wave (32 lanes/node, 4 ch/lane). Edge loop unrolled x4 for MLP.
template<int CH, bool INT8IN, bool HASBIAS, bool LN>
__global__ __launch_bounds__(256) void agg_kernel(const void* __restrict__ H_v,
                                                  const int* __restrict__ row_start,
                                                  const int* __restrict__ csr_src,
                                                  const float* __restrict__ dinv,
                                                  const float* __restrict__ cw,
                                                  const float* __restrict__ bias,
                                                  const float* __restrict__ gamma,
                                                  const float* __restrict__ beta,
                                                  void* __restrict__ out_v, int n) {
    constexpr int SUBW = 32;                        // lanes per node
    static_assert(CH == SUBW * 4, "layout");
    const int lane = threadIdx.x & 63;
    const int wid  = threadIdx.x >> 6;
    int node = blockIdx.x * 8 + wid * 2 + (lane >> 5);
    if (node >= n) return;
    const int slane = lane & (SUBW - 1);
    const int c0 = slane * 4;

    const unsigned char*  H8  = (const unsigned char*)H_v;
    const unsigned short* H16 = (const unsigned short*)H_v;

    const float dn = dinv[node];
    const int e0 = row_start[node], e1 = row_start[node + 1];

    float acc[4];
    #define LOAD4(sidx, v0, v1, v2, v3)                                             \
        float v0, v1, v2, v3;                                                       \
        if (INT8IN) {                                                               \
            unsigned int p = *(const unsigned int*)&H8[(size_t)(sidx) * CH + c0];   \
            v0 = (float)(int)(signed char)(p & 0xff);                               \
            v1 = (float)(int)(signed char)((p >> 8) & 0xff);                        \
            v2 = (float)(int)(signed char)((p >> 16) & 0xff);                       \
            v3 = (float)(int)(signed char)(p >> 24);                                \
        } else {                                                                    \
            ushort4 hh = *(const ushort4*)&H16[(size_t)(sidx) * CH + c0];           \
            v0 = bf2f(hh.x); v1 = bf2f(hh.y); v2 = bf2f(hh.z); v3 = bf2f(hh.w);     \
        }
    {   // self loop: coeff = dn * cw[node]
        float c = dn * cw[node];
        LOAD4(node, h0, h1, h2, h3)
        acc[0] = h0 * c; acc[1] = h1 * c; acc[2] = h2 * c; acc[3] = h3 * c;
    }
    int e = e0;
    for (; e + 4 <= e1; e += 4) {
        int s0 = csr_src[e + 0], s1 = csr_src[e + 1];
        int s2 = csr_src[e + 2], s3 = csr_src[e + 3];
        float w0 = cw[s0] * dn, w1 = cw[s1] * dn;
        float w2 = cw[s2] * dn, w3 = cw[s3] * dn;
        LOAD4(s0, a0, a1, a2, a3)
        LOAD4(s1, b0, b1, b2, b3)
        LOAD4(s2, c0v, c1v, c2v, c3v)
        LOAD4(s3, d0, d1, d2, d3)
        acc[0] += a0 * w0;  acc[1] += a1 * w0;  acc[2] += a2 * w0;  acc[3] += a3 * w0;
        acc[0] += b0 * w1;  acc[1] += b1 * w1;  acc[2] += b2 * w1;  acc[3] += b3 * w1;
        acc[0] += c0v * w2; acc[1] += c1v * w2; acc[2] += c2v * w2; acc[3] += c3v * w2;
        acc[0] += d0 * w3;  acc[1] += d1 * w3;  acc[2] += d2 * w3;  acc[3] += d3 * w3;
    }
    for (; e < e1; ++e) {
        int s = csr_src[e];
        float c = cw[s] * dn;
        LOAD4(s, h0, h1, h2, h3)
        acc[0] += h0 * c; acc[1] += h1 * c; acc[2] += h2 * c; acc[3] += h3 * c;
    }
    #undef LOAD4

    if (HASBIAS) {
        float4 bi = *(const float4*)&bias[c0];
        acc[0] += bi.x; acc[1] += bi.y; acc[2] += bi.z; acc[3] += bi.w;
    }

    if (LN) {
        // fused LayerNorm over the sub-wave (32 lanes hold the full row)
        float s = acc[0] + acc[1] + acc[2] + acc[3];
        float ss = acc[0]*acc[0] + acc[1]*acc[1] + acc[2]*acc[2] + acc[3]*acc[3];
        #pragma unroll
        for (int off = SUBW / 2; off; off >>= 1) {
            s  += __shfl_xor(s, off);
            ss += __shfl_xor(ss, off);
        }
        float mu  = s * (1.f / (float)CH);
        float var = ss * (1.f / (float)CH) - mu * mu;
        float rstd = rsqrtf(var + 1e-5f);
        float4 g = *(const float4*)&gamma[c0];
        float4 b = *(const float4*)&beta[c0];
        f32x4 o;
        o[0] = (acc[0] - mu) * rstd * g.x + b.x;
        o[1] = (acc[1] - mu) * rstd * g.y + b.y;
        o[2] = (acc[2] - mu) * rstd * g.z + b.z;
        o[3] = (acc[3] - mu) * rstd * g.w + b.w;
        float* out = (float*)out_v;
        __builtin_nontemporal_store(o, (f32x4*)&out[(size_t)node * CH + c0]);  // final out: write-only
    } else {
        // bf16 output (re-read by next gemm as MFMA A-operand)
        ushort4 o4;
        o4.x = f2bf(acc[0]); o4.y = f2bf(acc[1]);
        o4.z = f2bf(acc[2]); o4.w = f2bf(acc[3]);
        unsigned short* out = (unsigned short*)out_v;
        *(ushort4*)&out[(size_t)node * CH + c0] = o4;
    }
}

extern "C" void kernel_launch(void* const* d_in, const int* in_sizes, int n_in,
                              void* d_out, int out_size, void* d_ws, size_t ws_size,
                              hipStream_t stream) {
    const float* x     = (const float*)d_in[0];
    const int*   ei    = (const int*)d_in[1];     // int32 (harness: integer -> const int*)
    const float* W1    = (const float*)d_in[2];
    const float* b1    = (const float*)d_in[3];
    const float* W2    = (const float*)d_in[4];
    const float* b2    = (const float*)d_in[5];
    const float* gamma = (const float*)d_in[6];
    const float* beta  = (const float*)d_in[7];
    float* out = (float*)d_out;

    const int N = in_sizes[0] / C_IN;
    const int E = in_sizes[1] / 2;
    const int* src = ei;
    const int* dst = ei + E;
    const int NBINS = (N + BIN_SIZE - 1) >> BIN_SHIFT;
    const int NBINA = (E + CHUNK_A - 1) / CHUNK_A;

    // workspace layout
    unsigned char*  xq  = (unsigned char*)d_ws;                     // N*128 B (x int8)
    unsigned short* xa  = (unsigned short*)(xq + (size_t)N * C_IN); // N*128 bf16 (S·x)
    unsigned short* g16 = xa + (size_t)N * C_IN;                    // N*256 bf16
    unsigned short* h2  = g16 + (size_t)N * C_HID;                  // N*128 bf16 (g@W2)
    unsigned short* w1p = h2 + (size_t)N * C_OUT;                   // 128*256
    unsigned short* w2p = w1p + C_IN * C_HID;                       // 256*128
    float* dinv   = (float*)(w2p + C_HID * C_OUT);                  // N
    float* dscale = dinv + N;                                       // N (dinv*xscale)
    float* xscale = dscale + N;                                     // N
    int*   row_start = (int*)(xscale + N);                          // N+1 (pad 4)
    int*   gbin_cnt  = row_start + N + 4;                           // NBINS_MAX
    int*   bin_base  = gbin_cnt + NBINS_MAX;                        // NBINS_MAX+4
    unsigned int* binned = (unsigned int*)(bin_base + NBINS_MAX + 4);  // NBINS_MAX*CAP
    int*   csr_src   = (int*)(binned + (size_t)NBINS_MAX * CAP);       // E

    hipMemsetAsync(gbin_cnt, 0, NBINS_MAX * sizeof(int), stream);

    // fused: quant x->int8 | pack W1 | pack W2 | bin-append edges
    prep_kernel<<<CVT_BLOCKS + 2 * PACK_BLOCKS + NBINA, 256, 0, stream>>>(
        x, xq, xscale, W1, w1p, W2, w2p, src, dst, binned, gbin_cnt, E, N);
    binscan_kernel<<<1, 1024, 0, stream>>>(gbin_cnt, bin_base, row_start, NBINS, N);
    bincsr_kernel<<<NBINS, 1024, 0, stream>>>(binned, bin_base, xscale,
                                              csr_src, row_start, dinv, dscale, N);

    // layer 1 (linearity): xa = S·x (int8+row-scale gather) ; g = relu(xa@W1 + b1)
    agg_kernel<C_IN, true, false, false><<<(N + 7) / 8, 256, 0, stream>>>(
        (const void*)xq, row_start, csr_src, dinv, dscale,
        nullptr, nullptr, nullptr, (void*)xa, N);
    gemm_mfma_kernel<C_IN, C_HID, true><<<512, 256, 0, stream>>>(xa, w1p, g16, b1, N);

    // layer 2: h2 = g@W2 (bf16) ; out = LN(S·h2 + b2)
    gemm_mfma_kernel<C_HID, C_OUT, false><<<512, 256, 0, stream>>>(g16, w2p, h2, nullptr, N);
    agg_kernel<C_OUT, false, true, true><<<(N + 7) / 8, 256, 0, stream>>>(
        (const void*)h2, row_start, csr_src, dinv, dinv, b2, gamma, beta, (void*)out, N);
}

// Round 20
// 229.382 us; speedup vs baseline: 6.1061x; 1.0704x over previous
//
#include <hip/hip_runtime.h>
#include <hip/hip_bf16.h>

// ---------------- constants ----------------
#define C_IN  128
#define C_HID 256
#define C_OUT 128

#define BIN_SHIFT 10
#define BIN_SIZE  1024
#define NBINS_MAX 128
#define CAP       32768          // per-bin capacity (mean ~16.3K for uniform random)
#define CHUNK_A   8192           // edges per bin-append block

typedef __attribute__((ext_vector_type(8))) short short8;
typedef __attribute__((ext_vector_type(4))) float f32x4;

static __device__ __forceinline__ unsigned short f2bf(float f) {
    __hip_bfloat16 h = __float2bfloat16(f);
    return __builtin_bit_cast(unsigned short, h);
}
static __device__ __forceinline__ float bf2f(unsigned short u) {
    unsigned int x = ((unsigned int)u) << 16;
    return __builtin_bit_cast(float, x);
}

// ---------------- fused prep: quant x->int8/row-scale | pack W1 | pack W2 | bin-append ----------------
static __device__ __forceinline__ void pack_one(const float* __restrict__ W,
                                                unsigned short* __restrict__ Wp,
                                                int o, int NKS, int M) {
    int j    = o & 7;
    int lane = (o >> 3) & 63;
    int rest = o >> 9;
    int ks = rest % NKS;
    int ct = rest / NKS;
    int k = ks * 32 + (lane >> 4) * 8 + j;
    int m = ct * 16 + (lane & 15);
    Wp[o] = f2bf(W[(size_t)k * M + m]);
}

#define CVT_BLOCKS   512
#define PACK_BLOCKS  128     // 32768 / 256

__global__ __launch_bounds__(256) void prep_kernel(const float* __restrict__ x,
                                                   unsigned char* __restrict__ xq,
                                                   float* __restrict__ xscale,
                                                   const float* __restrict__ W1,
                                                   unsigned short* __restrict__ w1p,
                                                   const float* __restrict__ W2,
                                                   unsigned short* __restrict__ w2p,
                                                   const int* __restrict__ src,
                                                   const int* __restrict__ dst,
                                                   unsigned int* __restrict__ binned,
                                                   int* __restrict__ gbin_cnt,
                                                   int e, int n) {
    __shared__ int lh[NBINS_MAX];    // sweep-1 local histogram
    __shared__ int lgb[NBINS_MAX];   // global base per bin for this block
    __shared__ int lh2[NBINS_MAX];   // sweep-2 rank counters
    const int b = blockIdx.x, tid = threadIdx.x;
    if (b < CVT_BLOCKS) {
        // int8 row quantization: 32 lanes per row, 8 rows per block, grid-stride
        const int slane = tid & 31;
        const int subrow = tid >> 5;
        for (int row = b * 8 + subrow; row < n; row += CVT_BLOCKS * 8) {
            float4 v = *(const float4*)&x[(size_t)row * C_IN + slane * 4];
            float m = fmaxf(fmaxf(fabsf(v.x), fabsf(v.y)), fmaxf(fabsf(v.z), fabsf(v.w)));
            #pragma unroll
            for (int off = 16; off; off >>= 1) m = fmaxf(m, __shfl_xor(m, off));
            float inv = (m > 0.f) ? 127.f / m : 0.f;
            int q0 = (int)rintf(v.x * inv), q1 = (int)rintf(v.y * inv);
            int q2 = (int)rintf(v.z * inv), q3 = (int)rintf(v.w * inv);
            unsigned int p = ((unsigned)q0 & 0xff) | (((unsigned)q1 & 0xff) << 8) |
                             (((unsigned)q2 & 0xff) << 16) | (((unsigned)q3 & 0xff) << 24);
            *(unsigned int*)&xq[(size_t)row * C_IN + slane * 4] = p;
            if (slane == 0) xscale[row] = m * (1.f / 127.f);
        }
    } else if (b < CVT_BLOCKS + PACK_BLOCKS) {
        pack_one(W1, w1p, (b - CVT_BLOCKS) * 256 + tid, C_IN / 32, C_HID);
    } else if (b < CVT_BLOCKS + 2 * PACK_BLOCKS) {
        pack_one(W2, w2p, (b - CVT_BLOCKS - PACK_BLOCKS) * 256 + tid, C_HID / 32, C_OUT);
    } else {
        const int cb = b - CVT_BLOCKS - 2 * PACK_BLOCKS;
        const int start = cb * CHUNK_A;
        const int end = min(start + CHUNK_A, e);
        const int nbins = (n + BIN_SIZE - 1) >> BIN_SHIFT;
        for (int j = tid; j < nbins; j += 256) { lh[j] = 0; lh2[j] = 0; }
        __syncthreads();
        for (int i = start + tid; i < end; i += 256) {
            unsigned d = (unsigned)dst[i], s = (unsigned)src[i];
            if (d < (unsigned)n && s < (unsigned)n)
                atomicAdd(&lh[d >> BIN_SHIFT], 1);
        }
        __syncthreads();
        for (int j = tid; j < nbins; j += 256) {
            int c = lh[j];
            lgb[j] = c ? atomicAdd(&gbin_cnt[j], c) : 0;
        }
        __syncthreads();
        for (int i = start + tid; i < end; i += 256) {
            unsigned d = (unsigned)dst[i], s = (unsigned)src[i];
            if (d < (unsigned)n && s < (unsigned)n) {
                int bin = d >> BIN_SHIFT;
                int r = atomicAdd(&lh2[bin], 1);
                int pos = lgb[bin] + r;
                if (pos < CAP)
                    binned[(size_t)bin * CAP + pos] = (s << BIN_SHIFT) | (d & (BIN_SIZE - 1));
            }
        }
    }
}

// ---------------- bin scan: exclusive scan of gbin_cnt[nbins] -> bin_base; row_start[n]=total
__global__ __launch_bounds__(1024) void binscan_kernel(const int* __restrict__ gbin_cnt,
                                                       int* __restrict__ bin_base,
                                                       int* __restrict__ row_start,
                                                       int nbins, int n) {
    const int tid = threadIdx.x, lane = tid & 63, w = tid >> 6;
    int v = (tid < nbins) ? gbin_cnt[tid] : 0;
    int x = v;
    #pragma unroll
    for (int off = 1; off < 64; off <<= 1) {
        int y = __shfl_up(x, off);
        if (lane >= off) x += y;
    }
    __shared__ int ws[16];
    if (lane == 63) ws[w] = x;
    __syncthreads();
    int woff = 0, total = 0;
    #pragma unroll
    for (int j = 0; j < 16; ++j) {
        int s = ws[j];
        if (j < w) woff += s;
        total += s;
    }
    if (tid < nbins) bin_base[tid] = woff + (x - v);
    if (tid == 0) { bin_base[nbins] = total; row_start[n] = total; }
}

// ---------------- per-bin CSR build: block b owns nodes [b*1024, b*1024+1024)
// also writes dinv and dscale = dinv*xscale
__global__ __launch_bounds__(1024) void bincsr_kernel(const unsigned int* __restrict__ binned,
                                                      const int* __restrict__ bin_base,
                                                      const float* __restrict__ xscale,
                                                      int* __restrict__ csr_src,
                                                      int* __restrict__ row_start,
                                                      float* __restrict__ dinv,
                                                      float* __restrict__ dscale, int n) {
    __shared__ int h[BIN_SIZE];
    __shared__ int ex[BIN_SIZE];
    __shared__ int ws[16];
    const int b = blockIdx.x, tid = threadIdx.x, lane = tid & 63, w = tid >> 6;
    h[tid] = 0;
    __syncthreads();
    const int base  = bin_base[b];
    int cnt_b = bin_base[b + 1] - base;
    if (cnt_b > CAP) cnt_b = CAP;                    // safety clamp
    const size_t boff = (size_t)b * CAP;
    for (int i = tid; i < cnt_b; i += BIN_SIZE)
        atomicAdd(&h[binned[boff + i] & (BIN_SIZE - 1)], 1);
    __syncthreads();
    const int v = h[tid];
    int x = v;
    #pragma unroll
    for (int off = 1; off < 64; off <<= 1) {
        int y = __shfl_up(x, off);
        if (lane >= off) x += y;
    }
    if (lane == 63) ws[w] = x;
    __syncthreads();
    int woff = 0;
    #pragma unroll
    for (int j = 0; j < 16; ++j)
        if (j < w) woff += ws[j];
    const int excl = woff + (x - v);
    ex[tid] = excl;
    const int node = b * BIN_SIZE + tid;
    if (node < n) {
        row_start[node] = base + excl;
        float di = rsqrtf((float)(v + 1));           // +1 self loop
        dinv[node] = di;
        dscale[node] = di * xscale[node];
    }
    __syncthreads();
    h[tid] = 0;                                      // reuse as rank counters
    __syncthreads();
    for (int i = tid; i < cnt_b; i += BIN_SIZE) {
        unsigned p = binned[boff + i];
        int dl = p & (BIN_SIZE - 1);
        int r = atomicAdd(&h[dl], 1);
        csr_src[base + ex[dl] + r] = (int)(p >> BIN_SHIFT);
    }
}

// ---------------- MFMA GEMM: C[n,M] = A[n,K] bf16 @ W[K,M] (packed bf16) ----------------
// Epilogue: optional relu(v+bias); output bf16, or int8 + per-row scale (dscale_out = dinv*max/127)
template<int K, int M, bool BIASRELU, bool OUTINT8>
__global__ __launch_bounds__(256) void gemm_mfma_kernel(const unsigned short* __restrict__ A,
                                                        const unsigned short* __restrict__ Wp,
                                                        void* __restrict__ C_v,
                                                        const float* __restrict__ bias,
                                                        const float* __restrict__ dinv,
                                                        float* __restrict__ dscale_out, int n) {
    constexpr int NKS = K / 32;
    constexpr int NCT = M / 16;
    __shared__ unsigned short wl[K * M];            // 64 KB
    const int tid  = threadIdx.x;
    const int lane = tid & 63;
    const int wid  = tid >> 6;

    for (int i = tid; i < K * M / 8; i += 256)
        *(uint4*)&wl[(size_t)i * 8] = *(const uint4*)&Wp[(size_t)i * 8];
    __syncthreads();

    const int ntiles = (n + 63) / 64;
    for (int t = blockIdx.x; t < ntiles; t += gridDim.x) {
        const int row0 = t * 64 + wid * 16;
        int arow = row0 + (lane & 15);
        if (arow > n - 1) arow = n - 1;             // clamp (garbage rows masked at store)
        const unsigned short* ap = A + (size_t)arow * K + (lane >> 4) * 8;

        short8 afrag[NKS];
        #pragma unroll
        for (int ks = 0; ks < NKS; ++ks)
            afrag[ks] = *(const short8*)(ap + ks * 32);

        f32x4 acc[NCT] = {};
        #pragma unroll
        for (int ks = 0; ks < NKS; ++ks) {
            #pragma unroll
            for (int ct = 0; ct < NCT; ++ct) {
                short8 b = *(const short8*)&wl[((ct * NKS + ks) * 64 + lane) * 8];
                acc[ct] = __builtin_amdgcn_mfma_f32_16x16x32_bf16(afrag[ks], b, acc[ct], 0, 0, 0);
            }
        }

        // C/D layout: col = lane&15, row = (lane>>4)*4 + r   [verified m89]
        const int crow0 = row0 + (lane >> 4) * 4;
        const int ccol  = lane & 15;
        if (OUTINT8) {
            // per-row int8 quantization: row's M cols live in the 16 lanes of this
            // lane>>4 group (NCT ct-tiles each). shuffle-max over the 16-lane group.
            #pragma unroll
            for (int r = 0; r < 4; ++r) {
                float m = 0.f;
                #pragma unroll
                for (int ct = 0; ct < NCT; ++ct) m = fmaxf(m, fabsf(acc[ct][r]));
                #pragma unroll
                for (int off = 1; off < 16; off <<= 1) m = fmaxf(m, __shfl_xor(m, off));
                float inv = (m > 0.f) ? 127.f / m : 0.f;
                int row = crow0 + r;
                if (row < n) {
                    #pragma unroll
                    for (int ct = 0; ct < NCT; ++ct) {
                        int q = (int)rintf(acc[ct][r] * inv);
                        ((signed char*)C_v)[(size_t)row * M + ct * 16 + ccol] = (signed char)q;
                    }
                    if (ccol == 0) dscale_out[row] = dinv[row] * m * (1.f / 127.f);
                }
            }
        } else {
            #pragma unroll
            for (int ct = 0; ct < NCT; ++ct) {
                float bv = BIASRELU ? bias[ct * 16 + ccol] : 0.f;
                #pragma unroll
                for (int r = 0; r < 4; ++r) {
                    int row = crow0 + r;
                    if (row < n) {
                        float v = acc[ct][r];
                        if (BIASRELU) v = fmaxf(v + bv, 0.f);
                        ((unsigned short*)C_v)[(size_t)row * M + ct * 16 + ccol] = f2bf(v);
                    }
                }
            }
        }
    }
}

// ---------------- aggregation: out = [bias +] cw[n]*dn*H[n] + sum cw[s]*dn*H[s]
// cw = dscale (int8 H: dinv*scale) or dinv (bf16 H). dn = dinv[node].
// CH=128: 2 nodes/wave (32 lanes/node, 4 ch/lane). Edge loop unrolled x4 for MLP.
template<int CH, bool INT8IN, bool HASBIAS, bool LN>
__global__ __launch_bounds__(256) void agg_kernel(const void* __restrict__ H_v,
                                                  const int* __restrict__ row_start,
                                                  const int* __restrict__ csr_src,
                                                  const float* __restrict__ dinv,
                                                  const float* __restrict__ cw,
                                                  const float* __restrict__ bias,
                                                  const float* __restrict__ gamma,
                                                  const float* __restrict__ beta,
                                                  void* __restrict__ out_v, int n) {
    constexpr int SUBW = 32;                        // lanes per node
    static_assert(CH == SUBW * 4, "layout");
    const int lane = threadIdx.x & 63;
    const int wid  = threadIdx.x >> 6;
    int node = blockIdx.x * 8 + wid * 2 + (lane >> 5);
    if (node >= n) return;
    const int slane = lane & (SUBW - 1);
    const int c0 = slane * 4;

    const unsigned char*  H8  = (const unsigned char*)H_v;
    const unsigned short* H16 = (const unsigned short*)H_v;

    const float dn = dinv[node];
    const int e0 = row_start[node], e1 = row_start[node + 1];

    float acc[4];
    #define LOAD4(sidx, v0, v1, v2, v3)                                             \
        float v0, v1, v2, v3;                                                       \
        if (INT8IN) {                                                               \
            unsigned int p = *(const unsigned int*)&H8[(size_t)(sidx) * CH + c0];   \
            v0 = (float)(int)(signed char)(p & 0xff);                               \
            v1 = (float)(int)(signed char)((p >> 8) & 0xff);                        \
            v2 = (float)(int)(signed char)((p >> 16) & 0xff);                       \
            v3 = (float)(int)(signed char)(p >> 24);                                \
        } else {                                                                    \
            ushort4 hh = *(const ushort4*)&H16[(size_t)(sidx) * CH + c0];           \
            v0 = bf2f(hh.x); v1 = bf2f(hh.y); v2 = bf2f(hh.z); v3 = bf2f(hh.w);     \
        }
    {   // self loop: coeff = dn * cw[node]
        float c = dn * cw[node];
        LOAD4(node, h0, h1, h2, h3)
        acc[0] = h0 * c; acc[1] = h1 * c; acc[2] = h2 * c; acc[3] = h3 * c;
    }
    int e = e0;
    for (; e + 4 <= e1; e += 4) {
        int s0 = csr_src[e + 0], s1 = csr_src[e + 1];
        int s2 = csr_src[e + 2], s3 = csr_src[e + 3];
        float w0 = cw[s0] * dn, w1 = cw[s1] * dn;
        float w2 = cw[s2] * dn, w3 = cw[s3] * dn;
        LOAD4(s0, a0, a1, a2, a3)
        LOAD4(s1, b0, b1, b2, b3)
        LOAD4(s2, c0v, c1v, c2v, c3v)
        LOAD4(s3, d0, d1, d2, d3)
        acc[0] += a0 * w0;  acc[1] += a1 * w0;  acc[2] += a2 * w0;  acc[3] += a3 * w0;
        acc[0] += b0 * w1;  acc[1] += b1 * w1;  acc[2] += b2 * w1;  acc[3] += b3 * w1;
        acc[0] += c0v * w2; acc[1] += c1v * w2; acc[2] += c2v * w2; acc[3] += c3v * w2;
        acc[0] += d0 * w3;  acc[1] += d1 * w3;  acc[2] += d2 * w3;  acc[3] += d3 * w3;
    }
    for (; e < e1; ++e) {
        int s = csr_src[e];
        float c = cw[s] * dn;
        LOAD4(s, h0, h1, h2, h3)
        acc[0] += h0 * c; acc[1] += h1 * c; acc[2] += h2 * c; acc[3] += h3 * c;
    }
    #undef LOAD4

    if (HASBIAS) {
        float4 bi = *(const float4*)&bias[c0];
        acc[0] += bi.x; acc[1] += bi.y; acc[2] += bi.z; acc[3] += bi.w;
    }

    if (LN) {
        // fused LayerNorm over the sub-wave (32 lanes hold the full row)
        float s = acc[0] + acc[1] + acc[2] + acc[3];
        float ss = acc[0]*acc[0] + acc[1]*acc[1] + acc[2]*acc[2] + acc[3]*acc[3];
        #pragma unroll
        for (int off = SUBW / 2; off; off >>= 1) {
            s  += __shfl_xor(s, off);
            ss += __shfl_xor(ss, off);
        }
        float mu  = s * (1.f / (float)CH);
        float var = ss * (1.f / (float)CH) - mu * mu;
        float rstd = rsqrtf(var + 1e-5f);
        float4 g = *(const float4*)&gamma[c0];
        float4 b = *(const float4*)&beta[c0];
        f32x4 o;
        o[0] = (acc[0] - mu) * rstd * g.x + b.x;
        o[1] = (acc[1] - mu) * rstd * g.y + b.y;
        o[2] = (acc[2] - mu) * rstd * g.z + b.z;
        o[3] = (acc[3] - mu) * rstd * g.w + b.w;
        float* out = (float*)out_v;
        __builtin_nontemporal_store(o, (f32x4*)&out[(size_t)node * CH + c0]);  // final out: write-only
    } else {
        // bf16 output (re-read by next gemm as MFMA A-operand)
        ushort4 o4;
        o4.x = f2bf(acc[0]); o4.y = f2bf(acc[1]);
        o4.z = f2bf(acc[2]); o4.w = f2bf(acc[3]);
        unsigned short* out = (unsigned short*)out_v;
        *(ushort4*)&out[(size_t)node * CH + c0] = o4;
    }
}

extern "C" void kernel_launch(void* const* d_in, const int* in_sizes, int n_in,
                              void* d_out, int out_size, void* d_ws, size_t ws_size,
                              hipStream_t stream) {
    const float* x     = (const float*)d_in[0];
    const int*   ei    = (const int*)d_in[1];     // int32 (harness: integer -> const int*)
    const float* W1    = (const float*)d_in[2];
    const float* b1    = (const float*)d_in[3];
    const float* W2    = (const float*)d_in[4];
    const float* b2    = (const float*)d_in[5];
    const float* gamma = (const float*)d_in[6];
    const float* beta  = (const float*)d_in[7];
    float* out = (float*)d_out;

    const int N = in_sizes[0] / C_IN;
    const int E = in_sizes[1] / 2;
    const int* src = ei;
    const int* dst = ei + E;
    const int NBINS = (N + BIN_SIZE - 1) >> BIN_SHIFT;
    const int NBINA = (E + CHUNK_A - 1) / CHUNK_A;

    // workspace layout
    unsigned char*  xq  = (unsigned char*)d_ws;                     // N*128 B (x int8)
    unsigned short* xa  = (unsigned short*)(xq + (size_t)N * C_IN); // N*128 bf16 (S·x)
    unsigned short* g16 = xa + (size_t)N * C_IN;                    // N*256 bf16
    unsigned char*  h8  = (unsigned char*)(g16 + (size_t)N * C_HID);// N*128 B (g@W2 int8)
    unsigned short* w1p = (unsigned short*)(h8 + (size_t)N * C_OUT);// 128*256
    unsigned short* w2p = w1p + C_IN * C_HID;                       // 256*128
    float* dinv    = (float*)(w2p + C_HID * C_OUT);                 // N
    float* dscale  = dinv + N;                                      // N (dinv*xscale)
    float* xscale  = dscale + N;                                    // N
    float* dscale2 = xscale + N;                                    // N (dinv*hscale)
    int*   row_start = (int*)(dscale2 + N);                         // N+1 (pad 4)
    int*   gbin_cnt  = row_start + N + 4;                           // NBINS_MAX
    int*   bin_base  = gbin_cnt + NBINS_MAX;                        // NBINS_MAX+4
    unsigned int* binned = (unsigned int*)(bin_base + NBINS_MAX + 4);  // NBINS_MAX*CAP
    int*   csr_src   = (int*)(binned + (size_t)NBINS_MAX * CAP);       // E

    hipMemsetAsync(gbin_cnt, 0, NBINS_MAX * sizeof(int), stream);

    // fused: quant x->int8 | pack W1 | pack W2 | bin-append edges
    prep_kernel<<<CVT_BLOCKS + 2 * PACK_BLOCKS + NBINA, 256, 0, stream>>>(
        x, xq, xscale, W1, w1p, W2, w2p, src, dst, binned, gbin_cnt, E, N);
    binscan_kernel<<<1, 1024, 0, stream>>>(gbin_cnt, bin_base, row_start, NBINS, N);
    bincsr_kernel<<<NBINS, 1024, 0, stream>>>(binned, bin_base, xscale,
                                              csr_src, row_start, dinv, dscale, N);

    // layer 1 (linearity): xa = S·x (int8 gather) ; g = relu(xa@W1 + b1)
    agg_kernel<C_IN, true, false, false><<<(N + 7) / 8, 256, 0, stream>>>(
        (const void*)xq, row_start, csr_src, dinv, dscale,
        nullptr, nullptr, nullptr, (void*)xa, N);
    gemm_mfma_kernel<C_IN, C_HID, true, false><<<512, 256, 0, stream>>>(
        xa, w1p, (void*)g16, b1, nullptr, nullptr, N);

    // layer 2: h8 = g@W2 (int8 + row scale) ; out = LN(S·h8 + b2)
    gemm_mfma_kernel<C_HID, C_OUT, false, true><<<512, 256, 0, stream>>>(
        g16, w2p, (void*)h8, nullptr, dinv, dscale2, N);
    agg_kernel<C_OUT, true, true, true><<<(N + 7) / 8, 256, 0, stream>>>(
        (const void*)h8, row_start, csr_src, dinv, dscale2, b2, gamma, beta, (void*)out, N);
}